// Round 10
// baseline (1523.785 us; speedup 1.0000x reference)
//
#include <hip/hip_runtime.h>
#include <hip/hip_bf16.h>
#include <math.h>

#define D_    512
#define NHH   8
#define DH_   64
#define T_    16
#define T1_   17
#define HWL   256
#define B__   2
#define NEGV  -1e9f

typedef __attribute__((ext_vector_type(8))) short short8;
typedef __attribute__((ext_vector_type(4))) short short4v;
typedef __attribute__((ext_vector_type(4))) float f32x4;
typedef __hip_bfloat16 bf16;

__device__ inline float wave_sum(float v){
  #pragma unroll
  for(int o=32;o>0;o>>=1) v += __shfl_xor(v,o,64);
  return v;
}
__device__ inline float b2f(unsigned short s){
  unsigned u = ((unsigned)s)<<16; float f; __builtin_memcpy(&f,&u,4); return f;
}
__device__ inline short f2bs(float f){
  bf16 h = __float2bfloat16(f); short s; __builtin_memcpy(&s,&h,2); return s;
}
__device__ inline void gload_lds16(const void* g, void* l){
  __builtin_amdgcn_global_load_lds((const __attribute__((address_space(1))) void*)g,
                                   (__attribute__((address_space(3))) void*)l, 16, 0, 0);
}

// ---------------- embedding + LN, bf16 out ----------------
__global__ __launch_bounds__(256) void embed_ln_kernel(
    const int* __restrict__ codes, const float* __restrict__ emb,
    const float* __restrict__ cls, const float* __restrict__ hpos,
    const float* __restrict__ wpos, const float* __restrict__ g,
    const float* __restrict__ bta, bf16* __restrict__ X){
  int row  = blockIdx.x*4 + (threadIdx.x>>6);
  int lane = threadIdx.x & 63;
  int hw = row % HWL; int bt = row / HWL; int t = bt % T1_; int bb = bt / T1_;
  float v[8];
  if(t < T_){
    int code = codes[(bb*T_ + t)*HWL + hw];
    const float4* ep = (const float4*)(emb  + (size_t)code*D_);
    const float4* hp = (const float4*)(hpos + (size_t)(hw & 15)*D_);
    const float4* wp = (const float4*)(wpos + (size_t)(hw >> 4)*D_);
    float4 a0=ep[lane*2], a1=ep[lane*2+1];
    float4 h0=hp[lane*2], h1=hp[lane*2+1];
    float4 w0=wp[lane*2], w1=wp[lane*2+1];
    v[0]=a0.x+h0.x+w0.x; v[1]=a0.y+h0.y+w0.y; v[2]=a0.z+h0.z+w0.z; v[3]=a0.w+h0.w+w0.w;
    v[4]=a1.x+h1.x+w1.x; v[5]=a1.y+h1.y+w1.y; v[6]=a1.z+h1.z+w1.z; v[7]=a1.w+h1.w+w1.w;
  } else {
    const float4* cp = (const float4*)cls;
    float4 c0=cp[lane*2], c1=cp[lane*2+1];
    v[0]=c0.x; v[1]=c0.y; v[2]=c0.z; v[3]=c0.w; v[4]=c1.x; v[5]=c1.y; v[6]=c1.z; v[7]=c1.w;
  }
  float s=0;
  #pragma unroll
  for(int j=0;j<8;j++) s += v[j];
  s = wave_sum(s);
  float mean = s*(1.f/512.f);
  float s2=0;
  #pragma unroll
  for(int j=0;j<8;j++){ float d0=v[j]-mean; s2 += d0*d0; }
  s2 = wave_sum(s2);
  float inv = rsqrtf(s2*(1.f/512.f) + 1e-5f);
  const float4* g4 = (const float4*)g; const float4* b4 = (const float4*)bta;
  float4 gv=g4[lane*2], gw=g4[lane*2+1], bv=b4[lane*2], bw=b4[lane*2+1];
  short4v r0 = { f2bs((v[0]-mean)*inv*gv.x+bv.x), f2bs((v[1]-mean)*inv*gv.y+bv.y),
                 f2bs((v[2]-mean)*inv*gv.z+bv.z), f2bs((v[3]-mean)*inv*gv.w+bv.w) };
  short4v r1 = { f2bs((v[4]-mean)*inv*gw.x+bw.x), f2bs((v[5]-mean)*inv*gw.y+bw.y),
                 f2bs((v[6]-mean)*inv*gw.z+bw.z), f2bs((v[7]-mean)*inv*gw.w+bw.w) };
  bf16* o = X + (size_t)row*D_;
  *(short4v*)&o[lane*8]     = r0;
  *(short4v*)&o[lane*8 + 4] = r1;
}

// ---------------- LayerNorm, bf16 in -> fp32 out (final) ----------------
__global__ __launch_bounds__(256) void ln_kernel(
    const bf16* __restrict__ in, float* __restrict__ out,
    const float* __restrict__ g, const float* __restrict__ bta,
    int c_rpb, int s_rpb){
  int row  = blockIdx.x*4 + (threadIdx.x>>6);
  int lane = threadIdx.x & 63;
  int bb = row / c_rpb; int rem = row - bb*c_rpb;
  short8 vv = *(const short8*)(in + ((size_t)bb*s_rpb + rem)*D_ + lane*8);
  float v[8]; float s=0;
  #pragma unroll
  for(int j=0;j<8;j++){ v[j] = b2f((unsigned short)vv[j]); s += v[j]; }
  s = wave_sum(s);
  float mean = s*(1.f/512.f);
  float s2=0;
  #pragma unroll
  for(int j=0;j<8;j++){ float d0=v[j]-mean; s2 += d0*d0; }
  s2 = wave_sum(s2);
  float inv = rsqrtf(s2*(1.f/512.f) + 1e-5f);
  const float4* g4 = (const float4*)g; const float4* b4 = (const float4*)bta;
  float4 gv=g4[lane*2], gw=g4[lane*2+1], bv=b4[lane*2], bw=b4[lane*2+1];
  float4 o0 = { (v[0]-mean)*inv*gv.x+bv.x, (v[1]-mean)*inv*gv.y+bv.y,
                (v[2]-mean)*inv*gv.z+bv.z, (v[3]-mean)*inv*gv.w+bv.w };
  float4 o1 = { (v[4]-mean)*inv*gw.x+bw.x, (v[5]-mean)*inv*gw.y+bw.y,
                (v[6]-mean)*inv*gw.z+bw.z, (v[7]-mean)*inv*gw.w+bw.w };
  float* o = out + (size_t)row*D_;
  *(float4*)&o[lane*8]     = o0;
  *(float4*)&o[lane*8 + 4] = o1;
}

// ---------------- LayerNorm, bf16 in -> bf16 out ----------------
__global__ __launch_bounds__(256) void ln_bf_kernel(
    const bf16* __restrict__ in, bf16* __restrict__ out,
    const float* __restrict__ g, const float* __restrict__ bta,
    int c_rpb, int s_rpb){
  int row  = blockIdx.x*4 + (threadIdx.x>>6);
  int lane = threadIdx.x & 63;
  int bb = row / c_rpb; int rem = row - bb*c_rpb;
  short8 vv = *(const short8*)(in + ((size_t)bb*s_rpb + rem)*D_ + lane*8);
  float v[8]; float s=0;
  #pragma unroll
  for(int j=0;j<8;j++){ v[j] = b2f((unsigned short)vv[j]); s += v[j]; }
  s = wave_sum(s);
  float mean = s*(1.f/512.f);
  float s2=0;
  #pragma unroll
  for(int j=0;j<8;j++){ float d0=v[j]-mean; s2 += d0*d0; }
  s2 = wave_sum(s2);
  float inv = rsqrtf(s2*(1.f/512.f) + 1e-5f);
  const float4* g4 = (const float4*)g; const float4* b4 = (const float4*)bta;
  float4 gv=g4[lane*2], gw=g4[lane*2+1], bv=b4[lane*2], bw=b4[lane*2+1];
  short4v r0 = { f2bs((v[0]-mean)*inv*gv.x+bv.x), f2bs((v[1]-mean)*inv*gv.y+bv.y),
                 f2bs((v[2]-mean)*inv*gv.z+bv.z), f2bs((v[3]-mean)*inv*gv.w+bv.w) };
  short4v r1 = { f2bs((v[4]-mean)*inv*gw.x+bw.x), f2bs((v[5]-mean)*inv*gw.y+bw.y),
                 f2bs((v[6]-mean)*inv*gw.z+bw.z), f2bs((v[7]-mean)*inv*gw.w+bw.w) };
  bf16* o = out + (size_t)row*D_;
  *(short4v*)&o[lane*8]     = r0;
  *(short4v*)&o[lane*8 + 4] = r1;
}

// ---------------- weight fp32[K][N] -> bf16[N][K], ALL layers at once ----------------
__global__ __launch_bounds__(256) void wconv_kernel(
    const float* sq, const float* sk, const float* sv, const float* so,
    const float* tq, const float* tk, const float* tv, const float* to,
    const float* w1, const float* w2, bf16* __restrict__ dst){
  __shared__ float sm[32][33];
  int z = blockIdx.z; int i = z/10, id = z - i*10;
  const size_t wo = (size_t)i*262144, mo = (size_t)i*524288;
  bf16* db = dst + (size_t)i*3145728;
  const float* src; bf16* d; int K, N;
  switch(id){
    case 0: src=sq+wo; d=db+0*262144;  K=512;  N=512;  break;
    case 1: src=sk+wo; d=db+1*262144;  K=512;  N=512;  break;
    case 2: src=sv+wo; d=db+2*262144;  K=512;  N=512;  break;
    case 3: src=so+wo; d=db+3*262144;  K=512;  N=512;  break;
    case 4: src=tq+wo; d=db+4*262144;  K=512;  N=512;  break;
    case 5: src=tk+wo; d=db+5*262144;  K=512;  N=512;  break;
    case 6: src=tv+wo; d=db+6*262144;  K=512;  N=512;  break;
    case 7: src=to+wo; d=db+7*262144;  K=512;  N=512;  break;
    case 8: src=w1+mo; d=db+2097152;   K=512;  N=1024; break;
    default:src=w2+mo; d=db+2621440;   K=1024; N=512;  break;
  }
  int n0 = blockIdx.x<<5, k0 = blockIdx.y<<5;
  if(n0 >= N || k0 >= K) return;
  int tx = threadIdx.x & 31, ty = threadIdx.x >> 5;
  #pragma unroll
  for(int j=0;j<4;j++) sm[ty+j*8][tx] = src[(size_t)(k0+ty+j*8)*N + n0+tx];
  __syncthreads();
  #pragma unroll
  for(int j=0;j<4;j++) d[(size_t)(n0+ty+j*8)*K + k0+tx] = __float2bfloat16(sm[tx][ty+j*8]);
}

// ======== 8-phase-style GEMM: BM=256, BN=128, BK=64, tri-buffer, counted vmcnt ========
// MODE 0: single out (width N), bias b0, tanh.  MODE 1: QKV 3-way split (N=1536, outs 512 wide).
template<int MODE>
__global__ __launch_bounds__(512) void gemm_8p(
    const bf16* __restrict__ A, const bf16* __restrict__ Wt,
    const float* __restrict__ b0, const float* __restrict__ b1, const float* __restrict__ b2,
    bf16* __restrict__ o0, bf16* __restrict__ o1, bf16* __restrict__ o2,
    int K, int N){
  __shared__ __align__(16) bf16 As[3][256*64];   // 3 x 32 KB
  __shared__ __align__(16) bf16 Bs[3][128*64];   // 3 x 16 KB
  const int tid  = threadIdx.x;
  const int lane = tid & 63;
  const int w    = tid >> 6;
  const int wr   = w >> 1;          // 0..3  -> 64-row group
  const int wc   = w & 1;           // 0..1  -> 64-col group
  const int row0 = blockIdx.y << 8;
  const int col0 = blockIdx.x << 7;

  size_t gA[4], gB[2];
  #pragma unroll
  for(int j=0;j<4;j++){
    int c = tid + j*512; int rw = c>>3; int ks = (c&7) ^ (rw&7);
    gA[j] = (size_t)(row0+rw)*K + (ks<<3);
  }
  #pragma unroll
  for(int j=0;j<2;j++){
    int c = tid + j*512; int rw = c>>3; int ks = (c&7) ^ (rw&7);
    gB[j] = (size_t)(col0+rw)*K + (ks<<3);
  }

  const int NT = K >> 6;
  // prologue: stage tiles 0 and 1 (6 loads each, FIFO order)
  #pragma unroll
  for(int tt=0; tt<2; ++tt){
    #pragma unroll
    for(int j=0;j<4;j++) gload_lds16(A  + gA[j] + tt*64, &As[tt][(size_t)(tid + j*512)*8]);
    #pragma unroll
    for(int j=0;j<2;j++) gload_lds16(Wt + gB[j] + tt*64, &Bs[tt][(size_t)(tid + j*512)*8]);
  }
  asm volatile("s_waitcnt vmcnt(6)" ::: "memory");   // tile 0 complete; tile 1 in flight
  __builtin_amdgcn_s_barrier();
  __builtin_amdgcn_sched_barrier(0);

  f32x4 acc[4][4] = {};
  for(int t=0; t<NT; ++t){
    const short8* Av = (const short8*)As[t%3];
    const short8* Bv = (const short8*)Bs[t%3];
    bf16* An = As[(t+2)%3];
    bf16* Bn = Bs[(t+2)%3];
    const bool pf = (t+2 < NT);
    const int kn = (t+2) << 6;
    // ---- phase 1: issue half the prefetch, B-frags + A-frags(0,1), 16 MFMA ----
    if(pf){
      gload_lds16(A  + gA[0] + kn, &An[(size_t)tid*8]);
      gload_lds16(A  + gA[1] + kn, &An[(size_t)(tid+512)*8]);
      gload_lds16(Wt + gB[0] + kn, &Bn[(size_t)tid*8]);
    }
    short8 bfr[4][2], af01[2][2];
    #pragma unroll
    for(int ni=0;ni<4;ni++)
      #pragma unroll
      for(int kk=0;kk<2;kk++){
        int rw2 = wc*64 + ni*16 + (lane&15);
        int s = (lane>>4) + kk*4;
        bfr[ni][kk] = Bv[rw2*8 + (s ^ (rw2&7))];
      }
    #pragma unroll
    for(int mi=0;mi<2;mi++)
      #pragma unroll
      for(int kk=0;kk<2;kk++){
        int rw2 = wr*64 + mi*16 + (lane&15);
        int s = (lane>>4) + kk*4;
        af01[mi][kk] = Av[rw2*8 + (s ^ (rw2&7))];
      }
    __builtin_amdgcn_s_setprio(1);
    #pragma unroll
    for(int mi=0;mi<2;mi++)
      #pragma unroll
      for(int ni=0;ni<4;ni++)
        #pragma unroll
        for(int kk=0;kk<2;kk++)
          acc[mi][ni] = __builtin_amdgcn_mfma_f32_16x16x32_bf16(af01[mi][kk], bfr[ni][kk], acc[mi][ni], 0,0,0);
    __builtin_amdgcn_s_setprio(0);
    // ---- phase 2: rest of prefetch, A-frags(2,3), 16 MFMA ----
    if(pf){
      gload_lds16(A  + gA[2] + kn, &An[(size_t)(tid+1024)*8]);
      gload_lds16(A  + gA[3] + kn, &An[(size_t)(tid+1536)*8]);
      gload_lds16(Wt + gB[1] + kn, &Bn[(size_t)(tid+512)*8]);
    }
    short8 af23[2][2];
    #pragma unroll
    for(int mi=0;mi<2;mi++)
      #pragma unroll
      for(int kk=0;kk<2;kk++){
        int rw2 = wr*64 + (mi+2)*16 + (lane&15);
        int s = (lane>>4) + kk*4;
        af23[mi][kk] = Av[rw2*8 + (s ^ (rw2&7))];
      }
    __builtin_amdgcn_s_setprio(1);
    #pragma unroll
    for(int mi=0;mi<2;mi++)
      #pragma unroll
      for(int ni=0;ni<4;ni++)
        #pragma unroll
        for(int kk=0;kk<2;kk++)
          acc[mi+2][ni] = __builtin_amdgcn_mfma_f32_16x16x32_bf16(af23[mi][kk], bfr[ni][kk], acc[mi+2][ni], 0,0,0);
    __builtin_amdgcn_s_setprio(0);
    // ---- end-of-iter: counted drain (tile t+1 must be resident; t+2 stays in flight) ----
    if(t < NT-1){
      if(pf) asm volatile("s_waitcnt vmcnt(6)" ::: "memory");
      else   asm volatile("s_waitcnt vmcnt(0)" ::: "memory");
      __builtin_amdgcn_s_barrier();
      __builtin_amdgcn_sched_barrier(0);
    }
  }
  // ---- epilogue ----
  if(MODE == 1){
    const int sel = col0 >> 9;
    bf16* outp = (sel==0) ? o0 : (sel==1 ? o1 : o2);
    const float* bp = (sel==0) ? b0 : (sel==1 ? b1 : b2);
    const int cb = (col0 & 511) + wc*64;
    #pragma unroll
    for(int mi=0;mi<4;mi++)
      #pragma unroll
      for(int r=0;r<4;r++){
        int row = row0 + wr*64 + mi*16 + (lane>>4)*4 + r;
        #pragma unroll
        for(int ni=0;ni<4;ni++){
          int col = cb + ni*16 + (lane&15);
          outp[(size_t)row*512 + col] = __float2bfloat16(acc[mi][ni][r] + bp[col]);
        }
      }
  } else {
    #pragma unroll
    for(int mi=0;mi<4;mi++)
      #pragma unroll
      for(int r=0;r<4;r++){
        int row = row0 + wr*64 + mi*16 + (lane>>4)*4 + r;
        #pragma unroll
        for(int ni=0;ni<4;ni++){
          int col = col0 + wc*64 + ni*16 + (lane&15);
          float v = tanhf(acc[mi][ni][r] + b0[col]);
          o0[(size_t)row*N + col] = __float2bfloat16(v);
        }
      }
  }
}

// ---------------- bf16 MFMA GEMM, 64x64 tile, BK=64, swizzled, dbuf (O-proj / MLP2) ----------------
template<int ACT, bool RES>
__global__ __launch_bounds__(256) void gemm_mfma64(
    const bf16* __restrict__ A, const bf16* __restrict__ Wt,
    const float* __restrict__ bias, bf16* __restrict__ outp,
    const bf16* __restrict__ resid, int K, int N, int c_rpb, int o_rpb){
  __shared__ __align__(16) bf16 As[2][64*64];
  __shared__ __align__(16) bf16 Bs[2][64*64];
  const int tid  = threadIdx.x;
  const int lane = tid & 63;
  const int w    = tid >> 6;
  const int row0 = blockIdx.y << 6;
  const int col0 = blockIdx.x << 6;
  const int mw = (w>>1)*32, nw = (w&1)*32;
  size_t ga[2], gb[2];
  #pragma unroll
  for(int r=0;r<2;r++){
    int c = (r*4+w)*64 + lane;
    int rw = c>>3;
    int ks = (c&7) ^ (rw&7);
    ga[r] = (size_t)(row0+rw)*K + (ks<<3);
    gb[r] = (size_t)(col0+rw)*K + (ks<<3);
  }
  f32x4 acc[2][2] = {};
  #pragma unroll
  for(int r=0;r<2;r++){
    gload_lds16(A  + ga[r], &As[0][(r*4+w)*512]);
    gload_lds16(Wt + gb[r], &Bs[0][(r*4+w)*512]);
  }
  __syncthreads();
  int cur = 0;
  for(int k0=0;k0<K;k0+=64){
    if(k0+64 < K){
      #pragma unroll
      for(int r=0;r<2;r++){
        gload_lds16(A  + ga[r] + k0+64, &As[cur^1][(r*4+w)*512]);
        gload_lds16(Wt + gb[r] + k0+64, &Bs[cur^1][(r*4+w)*512]);
      }
    }
    const short8* Av = (const short8*)As[cur];
    const short8* Bv = (const short8*)Bs[cur];
    #pragma unroll
    for(int kk=0;kk<2;kk++){
      const int slot = (lane>>4) + kk*4;
      short8 af[2], bfr[2];
      #pragma unroll
      for(int mi=0;mi<2;mi++){ int rw = mw + mi*16 + (lane&15); af[mi]  = Av[rw*8 + (slot ^ (rw&7))]; }
      #pragma unroll
      for(int ni=0;ni<2;ni++){ int rw = nw + ni*16 + (lane&15); bfr[ni] = Bv[rw*8 + (slot ^ (rw&7))]; }
      #pragma unroll
      for(int mi=0;mi<2;mi++)
        #pragma unroll
        for(int ni=0;ni<2;ni++)
          acc[mi][ni] = __builtin_amdgcn_mfma_f32_16x16x32_bf16(af[mi], bfr[ni], acc[mi][ni], 0,0,0);
    }
    __syncthreads();
    cur ^= 1;
  }
  #pragma unroll
  for(int mi=0;mi<2;mi++){
    #pragma unroll
    for(int r=0;r<4;r++){
      int row = row0 + mw + mi*16 + (lane>>4)*4 + r;
      int bb = row / c_rpb;
      size_t orow = (size_t)bb*o_rpb + (row - bb*c_rpb);
      #pragma unroll
      for(int ni=0;ni<2;ni++){
        int col = col0 + nw + ni*16 + (lane&15);
        float v = acc[mi][ni][r] + bias[col];
        if(ACT==1) v = tanhf(v);
        if(RES) v += __bfloat162float(resid[orow*(size_t)N + col]);
        outp[orow*(size_t)N + col] = __float2bfloat16(v);
      }
    }
  }
}

// ---------------- spatial 3x3 windowed attention: paired bf16, 2 heads/wave ----------------
__global__ __launch_bounds__(256) void spatial_attn_kernel(
    const bf16* __restrict__ Q, const bf16* __restrict__ K,
    const bf16* __restrict__ V, bf16* __restrict__ O){
  int loc = blockIdx.x;
  int hw = loc & 255;
  int hh = hw >> 4, ww = hw & 15;
  int tid = threadIdx.x, lane = tid & 63, w = tid >> 6;
  int h = w*2 + (lane>>5);
  int j = lane & 31;
  size_t base = (size_t)loc*D_ + h*DH_ + 2*j;
  unsigned uq = *(const unsigned*)&Q[base];
  float q0 = b2f((unsigned short)uq), q1 = b2f((unsigned short)(uq>>16));
  float lg[9]; int nrow[9];
  #pragma unroll
  for(int s=0;s<9;s++){
    int a = s/3 - 1, b2_ = s%3 - 1;
    int nh = hh + a, nw = ww + b2_;
    bool ok = ((unsigned)nh < 16u) && ((unsigned)nw < 16u);
    nrow[s] = ok ? (loc - hw + (nh<<4) + nw) : -1;
    float p = 0.f;
    if(ok){
      unsigned uk = *(const unsigned*)&K[(size_t)nrow[s]*D_ + h*DH_ + 2*j];
      p = q0*b2f((unsigned short)uk) + q1*b2f((unsigned short)(uk>>16));
    }
    #pragma unroll
    for(int o=16;o>0;o>>=1) p += __shfl_xor(p, o, 64);
    lg[s] = ok ? p*0.125f : NEGV;
  }
  float m = lg[0];
  #pragma unroll
  for(int s=1;s<9;s++) m = fmaxf(m, lg[s]);
  float den = 0.f, wv[9];
  #pragma unroll
  for(int s=0;s<9;s++){ wv[s] = __expf(lg[s]-m); den += wv[s]; }
  float inv = 1.f/den;
  float a0 = 0.f, a1 = 0.f;
  #pragma unroll
  for(int s=0;s<9;s++){
    if(nrow[s] >= 0){
      unsigned uv = *(const unsigned*)&V[(size_t)nrow[s]*D_ + h*DH_ + 2*j];
      a0 += wv[s]*b2f((unsigned short)uv);
      a1 += wv[s]*b2f((unsigned short)(uv>>16));
    }
  }
  unsigned up = (unsigned)(unsigned short)f2bs(a0*inv) | ((unsigned)(unsigned short)f2bs(a1*inv) << 16);
  *(unsigned*)&O[base] = up;
}

// ---------------- fused temporal attention: block = (b,hw), 8 waves = 8 heads ----------------
__global__ __launch_bounds__(512) void fused_tattn(
    const bf16* __restrict__ Qb, const bf16* __restrict__ Kb, const bf16* __restrict__ Vb,
    bf16* __restrict__ O, float* __restrict__ kout, float* __restrict__ vout,
    float* __restrict__ ltout, int write_lt){
  __shared__ __align__(16) bf16 Qs[17*520];
  __shared__ __align__(16) bf16 Ks[17*520];
  __shared__ __align__(16) bf16 Vs[17*512];
  __shared__ float Ws[8][17][18];
  const int tid = threadIdx.x, w = tid>>6, lane = tid&63;
  const int hw = blockIdx.x & 255, b = blockIdx.x >> 8;
  const size_t tstr = (size_t)HWL*D_;
  const size_t rb0 = ((size_t)(b*T1_)*HWL + hw)*D_;
  for(int t=w; t<17; t+=8){
    size_t src = rb0 + (size_t)t*tstr + lane*8;
    *(short8*)&Qs[t*520 + lane*8] = *(const short8*)&Qb[src];
    *(short8*)&Ks[t*520 + lane*8] = *(const short8*)&Kb[src];
    *(short8*)&Vs[t*512 + lane*8] = *(const short8*)&Vb[src];
  }
  __syncthreads();
  {
    int i = lane & 31;
    float freq = __expf(-9.210340372f * (float)i * (1.f/32.f));
    bf16* P = (lane < 32) ? Qs : Ks;
    #pragma unroll
    for(int t=0;t<17;t++){
      float sn, cs; __sincosf((float)t*freq, &sn, &cs);
      int idx = t*520 + w*64 + i;
      float x1 = __bfloat162float(P[idx]);
      float x2 = __bfloat162float(P[idx+32]);
      P[idx]    = __float2bfloat16(x1*cs - x2*sn);
      P[idx+32] = __float2bfloat16(x2*cs + x1*sn);
    }
  }
  __syncthreads();
  {
    size_t eb = (((size_t)(b*HWL + hw)*NHH + w)*16)*64 + lane;
    #pragma unroll
    for(int t=0;t<16;t++){
      kout[eb + t*64] = __bfloat162float(Ks[t*520 + w*64 + lane]);
      vout[eb + t*64] = __bfloat162float(Vs[t*512 + w*64 + lane]);
    }
  }
  size_t lb = ((size_t)(b*HWL + hw)*NHH + w)*289;
  for(int p=lane; p<289; p+=64){
    int t = p/17, u = p - t*17;
    float d = 0.f;
    #pragma unroll
    for(int jj=0;jj<8;jj++){
      short8 qq = *(short8*)&Qs[t*520 + w*64 + jj*8];
      short8 kk = *(short8*)&Ks[u*520 + w*64 + jj*8];
      #pragma unroll
      for(int e=0;e<8;e++) d += b2f((unsigned short)qq[e]) * b2f((unsigned short)kk[e]);
    }
    bool masked = (u > t) || (t == 16 && u == 16);
    float lg = masked ? NEGV : d*0.125f;
    Ws[w][t][u] = lg;
    if(write_lt) ltout[lb + t*17 + u] = lg;
  }
  __syncthreads();
  if(lane < 17){
    float m = -1e30f;
    #pragma unroll
    for(int u=0;u<17;u++) m = fmaxf(m, Ws[w][lane][u]);
    float den = 0.f, e[17];
    #pragma unroll
    for(int u=0;u<17;u++){ e[u] = __expf(Ws[w][lane][u]-m); den += e[u]; }
    float inv = 1.f/den;
    #pragma unroll
    for(int u=0;u<17;u++) Ws[w][lane][u] = e[u]*inv;
  }
  __syncthreads();
  float Vr[17];
  #pragma unroll
  for(int u=0;u<17;u++) Vr[u] = __bfloat162float(Vs[u*512 + w*64 + lane]);
  #pragma unroll
  for(int t=0;t<17;t++){
    float acc = 0.f;
    #pragma unroll
    for(int u=0;u<17;u++) acc += Ws[w][t][u]*Vr[u];
    O[rb0 + (size_t)t*tstr + w*64 + lane] = __float2bfloat16(acc);
  }
}

// ---------------- frame-0 spatial mean broadcast, row-coalesced ----------------
__global__ __launch_bounds__(256) void avg_frame0_kernel(bf16* __restrict__ X){
  int b = blockIdx.x >> 3, c = blockIdx.x & 7;
  int ro = threadIdx.x >> 6, dd = threadIdx.x & 63;
  size_t base = ((size_t)(b*T1_)*HWL)*D_ + c*64 + dd;
  float acc = 0.f;
  for(int r=ro; r<256; r+=4) acc += __bfloat162float(X[base + (size_t)r*D_]);
  __shared__ float sm[4][64];
  sm[ro][dd] = acc;
  __syncthreads();
  float v = (sm[0][dd]+sm[1][dd]+sm[2][dd]+sm[3][dd])*(1.f/256.f);
  bf16 bv = __float2bfloat16(v);
  for(int r=ro; r<256; r+=4) X[base + (size_t)r*D_] = bv;
}

extern "C" void kernel_launch(void* const* d_in, const int* in_sizes, int n_in,
                              void* d_out, int out_size, void* d_ws, size_t ws_size,
                              hipStream_t stream){
  const int*   codes = (const int*)  d_in[0];
  const float* emb   = (const float*)d_in[1];
  const float* cls   = (const float*)d_in[2];
  const float* hpos  = (const float*)d_in[3];
  const float* wpos  = (const float*)d_in[4];
  const float* eng   = (const float*)d_in[5];
  const float* enb   = (const float*)d_in[6];
  const float* sn_g  = (const float*)d_in[7];
  const float* sn_b  = (const float*)d_in[8];
  const float* s_wq  = (const float*)d_in[9];
  const float* s_bq  = (const float*)d_in[10];
  const float* s_wk  = (const float*)d_in[11];
  const float* s_bk  = (const float*)d_in[12];
  const float* s_wv  = (const float*)d_in[13];
  const float* s_bv  = (const float*)d_in[14];
  const float* s_wo  = (const float*)d_in[15];
  const float* s_bo  = (const float*)d_in[16];
  const float* tn_g  = (const float*)d_in[17];
  const float* tn_b  = (const float*)d_in[18];
  const float* t_wq  = (const float*)d_in[19];
  const float* t_bq  = (const float*)d_in[20];
  const float* t_wk  = (const float*)d_in[21];
  const float* t_bk  = (const float*)d_in[22];
  const float* t_wv  = (const float*)d_in[23];
  const float* t_bv  = (const float*)d_in[24];
  const float* t_wo  = (const float*)d_in[25];
  const float* t_bo  = (const float*)d_in[26];
  const float* mn_g  = (const float*)d_in[27];
  const float* mn_b  = (const float*)d_in[28];
  const float* mw1   = (const float*)d_in[29];
  const float* mb1   = (const float*)d_in[30];
  const float* mw2   = (const float*)d_in[31];
  const float* mb2   = (const float*)d_in[32];
  const float* fn_g  = (const float*)d_in[33];
  const float* fn_b  = (const float*)d_in[34];

  const size_t NX = 4456448;               // B*T1*HW*D
  bf16* Xb  = (bf16*)d_ws;                 // residual stream, bf16
  bf16* XNb = Xb  + NX;
  bf16* Qb  = XNb + NX;
  bf16* Kb  = Qb  + NX;
  bf16* Vb  = Kb  + NX;
  bf16* Wt  = Vb  + NX;                    // 6 layers x 3,145,728 bf16
  bf16* HIDb= Qb;                          // [8704][1024] bf16, aliases Qb+Kb

  float* out0 = (float*)d_out;
  float* out1 = out0 + NX;
  float* out2 = out1 + 1183744;
  float* out3 = out2 + 25165824;

  const int RS = B__*T_*HWL;           // 8192
  const int RT = B__*T1_*HWL;          // 8704
  dim3 gQs8(12, 32);                   // QKV spatial: N=1536/128, M=8192/256
  dim3 gQt8(12, 34);                   // QKV temporal: M=8704/256
  dim3 gM18(8, 34);                    // MLP1: N=1024/128
  dim3 g64s(8, 128);                   // N=512, M=8192 (64^2)
  dim3 g64t(8, 136);                   // N=512, M=8704 (64^2)
  dim3 wcg(32, 32, 60);

  embed_ln_kernel<<<RT/4, 256, 0, stream>>>(codes, emb, cls, hpos, wpos, eng, enb, Xb);
  wconv_kernel<<<wcg,256,0,stream>>>(s_wq, s_wk, s_wv, s_wo, t_wq, t_wk, t_wv, t_wo, mw1, mw2, Wt);

  for(int i=0;i<6;i++){
    bf16* Wl = Wt + (size_t)i*3145728;
    // ---- spatial windowed attention ----
    ln_bf_kernel<<<RS/4,256,0,stream>>>(Xb, XNb, sn_g+i*D_, sn_b+i*D_, T_*HWL, T1_*HWL);
    gemm_8p<1><<<gQs8,512,0,stream>>>(XNb, Wl, s_bq+i*D_, s_bk+i*D_, s_bv+i*D_,
                                      Qb, Kb, Vb, 512, 1536);
    spatial_attn_kernel<<<RS,256,0,stream>>>(Qb, Kb, Vb, XNb);
    gemm_mfma64<0,true><<<g64s,256,0,stream>>>(XNb, Wl+3*262144, s_bo+i*D_, Xb, Xb, 512, 512, T_*HWL, T1_*HWL);
    // ---- temporal RoPE causal attention (fused) ----
    ln_bf_kernel<<<RT/4,256,0,stream>>>(Xb, XNb, tn_g+i*D_, tn_b+i*D_, T1_*HWL, T1_*HWL);
    gemm_8p<1><<<gQt8,512,0,stream>>>(XNb, Wl+4*262144, t_bq+i*D_, t_bk+i*D_, t_bv+i*D_,
                                      Qb, Kb, Vb, 512, 1536);
    fused_tattn<<<512,512,0,stream>>>(Qb, Kb, Vb, XNb,
                                      out2+(size_t)i*4194304, out3+(size_t)i*4194304,
                                      out1, (i==5)?1:0);
    gemm_mfma64<0,true><<<g64t,256,0,stream>>>(XNb, Wl+7*262144, t_bo+i*D_, Xb, Xb, 512, 512, RT, RT);
    avg_frame0_kernel<<<16,256,0,stream>>>(Xb);
    // ---- MLP ----
    ln_bf_kernel<<<RT/4,256,0,stream>>>(Xb, XNb, mn_g+i*D_, mn_b+i*D_, T1_*HWL, T1_*HWL);
    gemm_8p<0><<<gM18,512,0,stream>>>(XNb, Wl+2097152, mb1+i*1024, nullptr, nullptr,
                                      HIDb, nullptr, nullptr, 512, 1024);
    gemm_mfma64<0,true><<<g64t,256,0,stream>>>(HIDb, Wl+2621440, mb2+i*D_, Xb, Xb, 1024, 512, RT, RT);
  }
  ln_kernel<<<RT/4,256,0,stream>>>(Xb, out0, fn_g, fn_b, T1_*HWL, T1_*HWL);
}

// Round 11
// 1386.379 us; speedup vs baseline: 1.0991x; 1.0991x over previous
//
#include <hip/hip_runtime.h>
#include <hip/hip_bf16.h>
#include <math.h>

#define D_    512
#define NHH   8
#define DH_   64
#define T_    16
#define T1_   17
#define HWL   256
#define B__   2
#define NEGV  -1e9f

typedef __attribute__((ext_vector_type(8))) short short8;
typedef __attribute__((ext_vector_type(4))) short short4v;
typedef __attribute__((ext_vector_type(4))) float f32x4;
typedef __hip_bfloat16 bf16;

__device__ inline float wave_sum(float v){
  #pragma unroll
  for(int o=32;o>0;o>>=1) v += __shfl_xor(v,o,64);
  return v;
}
__device__ inline float b2f(unsigned short s){
  unsigned u = ((unsigned)s)<<16; float f; __builtin_memcpy(&f,&u,4); return f;
}
__device__ inline short f2bs(float f){
  bf16 h = __float2bfloat16(f); short s; __builtin_memcpy(&s,&h,2); return s;
}
__device__ inline void gload_lds16(const void* g, void* l){
  __builtin_amdgcn_global_load_lds((const __attribute__((address_space(1))) void*)g,
                                   (__attribute__((address_space(3))) void*)l, 16, 0, 0);
}

// ---------------- embedding + LN, bf16 out ----------------
__global__ __launch_bounds__(256) void embed_ln_kernel(
    const int* __restrict__ codes, const float* __restrict__ emb,
    const float* __restrict__ cls, const float* __restrict__ hpos,
    const float* __restrict__ wpos, const float* __restrict__ g,
    const float* __restrict__ bta, bf16* __restrict__ X){
  int row  = blockIdx.x*4 + (threadIdx.x>>6);
  int lane = threadIdx.x & 63;
  int hw = row % HWL; int bt = row / HWL; int t = bt % T1_; int bb = bt / T1_;
  float v[8];
  if(t < T_){
    int code = codes[(bb*T_ + t)*HWL + hw];
    const float4* ep = (const float4*)(emb  + (size_t)code*D_);
    const float4* hp = (const float4*)(hpos + (size_t)(hw & 15)*D_);
    const float4* wp = (const float4*)(wpos + (size_t)(hw >> 4)*D_);
    float4 a0=ep[lane*2], a1=ep[lane*2+1];
    float4 h0=hp[lane*2], h1=hp[lane*2+1];
    float4 w0=wp[lane*2], w1=wp[lane*2+1];
    v[0]=a0.x+h0.x+w0.x; v[1]=a0.y+h0.y+w0.y; v[2]=a0.z+h0.z+w0.z; v[3]=a0.w+h0.w+w0.w;
    v[4]=a1.x+h1.x+w1.x; v[5]=a1.y+h1.y+w1.y; v[6]=a1.z+h1.z+w1.z; v[7]=a1.w+h1.w+w1.w;
  } else {
    const float4* cp = (const float4*)cls;
    float4 c0=cp[lane*2], c1=cp[lane*2+1];
    v[0]=c0.x; v[1]=c0.y; v[2]=c0.z; v[3]=c0.w; v[4]=c1.x; v[5]=c1.y; v[6]=c1.z; v[7]=c1.w;
  }
  float s=0;
  #pragma unroll
  for(int j=0;j<8;j++) s += v[j];
  s = wave_sum(s);
  float mean = s*(1.f/512.f);
  float s2=0;
  #pragma unroll
  for(int j=0;j<8;j++){ float d0=v[j]-mean; s2 += d0*d0; }
  s2 = wave_sum(s2);
  float inv = rsqrtf(s2*(1.f/512.f) + 1e-5f);
  const float4* g4 = (const float4*)g; const float4* b4 = (const float4*)bta;
  float4 gv=g4[lane*2], gw=g4[lane*2+1], bv=b4[lane*2], bw=b4[lane*2+1];
  short4v r0 = { f2bs((v[0]-mean)*inv*gv.x+bv.x), f2bs((v[1]-mean)*inv*gv.y+bv.y),
                 f2bs((v[2]-mean)*inv*gv.z+bv.z), f2bs((v[3]-mean)*inv*gv.w+bv.w) };
  short4v r1 = { f2bs((v[4]-mean)*inv*gw.x+bw.x), f2bs((v[5]-mean)*inv*gw.y+bw.y),
                 f2bs((v[6]-mean)*inv*gw.z+bw.z), f2bs((v[7]-mean)*inv*gw.w+bw.w) };
  bf16* o = X + (size_t)row*D_;
  *(short4v*)&o[lane*8]     = r0;
  *(short4v*)&o[lane*8 + 4] = r1;
}

// ---------------- LayerNorm, bf16 in -> fp32 out (final) ----------------
__global__ __launch_bounds__(256) void ln_kernel(
    const bf16* __restrict__ in, float* __restrict__ out,
    const float* __restrict__ g, const float* __restrict__ bta,
    int c_rpb, int s_rpb){
  int row  = blockIdx.x*4 + (threadIdx.x>>6);
  int lane = threadIdx.x & 63;
  int bb = row / c_rpb; int rem = row - bb*c_rpb;
  short8 vv = *(const short8*)(in + ((size_t)bb*s_rpb + rem)*D_ + lane*8);
  float v[8]; float s=0;
  #pragma unroll
  for(int j=0;j<8;j++){ v[j] = b2f((unsigned short)vv[j]); s += v[j]; }
  s = wave_sum(s);
  float mean = s*(1.f/512.f);
  float s2=0;
  #pragma unroll
  for(int j=0;j<8;j++){ float d0=v[j]-mean; s2 += d0*d0; }
  s2 = wave_sum(s2);
  float inv = rsqrtf(s2*(1.f/512.f) + 1e-5f);
  const float4* g4 = (const float4*)g; const float4* b4 = (const float4*)bta;
  float4 gv=g4[lane*2], gw=g4[lane*2+1], bv=b4[lane*2], bw=b4[lane*2+1];
  float4 o0 = { (v[0]-mean)*inv*gv.x+bv.x, (v[1]-mean)*inv*gv.y+bv.y,
                (v[2]-mean)*inv*gv.z+bv.z, (v[3]-mean)*inv*gv.w+bv.w };
  float4 o1 = { (v[4]-mean)*inv*gw.x+bw.x, (v[5]-mean)*inv*gw.y+bw.y,
                (v[6]-mean)*inv*gw.z+bw.z, (v[7]-mean)*inv*gw.w+bw.w };
  float* o = out + (size_t)row*D_;
  *(float4*)&o[lane*8]     = o0;
  *(float4*)&o[lane*8 + 4] = o1;
}

// ---------------- LayerNorm, bf16 in -> bf16 out ----------------
__global__ __launch_bounds__(256) void ln_bf_kernel(
    const bf16* __restrict__ in, bf16* __restrict__ out,
    const float* __restrict__ g, const float* __restrict__ bta,
    int c_rpb, int s_rpb){
  int row  = blockIdx.x*4 + (threadIdx.x>>6);
  int lane = threadIdx.x & 63;
  int bb = row / c_rpb; int rem = row - bb*c_rpb;
  short8 vv = *(const short8*)(in + ((size_t)bb*s_rpb + rem)*D_ + lane*8);
  float v[8]; float s=0;
  #pragma unroll
  for(int j=0;j<8;j++){ v[j] = b2f((unsigned short)vv[j]); s += v[j]; }
  s = wave_sum(s);
  float mean = s*(1.f/512.f);
  float s2=0;
  #pragma unroll
  for(int j=0;j<8;j++){ float d0=v[j]-mean; s2 += d0*d0; }
  s2 = wave_sum(s2);
  float inv = rsqrtf(s2*(1.f/512.f) + 1e-5f);
  const float4* g4 = (const float4*)g; const float4* b4 = (const float4*)bta;
  float4 gv=g4[lane*2], gw=g4[lane*2+1], bv=b4[lane*2], bw=b4[lane*2+1];
  short4v r0 = { f2bs((v[0]-mean)*inv*gv.x+bv.x), f2bs((v[1]-mean)*inv*gv.y+bv.y),
                 f2bs((v[2]-mean)*inv*gv.z+bv.z), f2bs((v[3]-mean)*inv*gv.w+bv.w) };
  short4v r1 = { f2bs((v[4]-mean)*inv*gw.x+bw.x), f2bs((v[5]-mean)*inv*gw.y+bw.y),
                 f2bs((v[6]-mean)*inv*gw.z+bw.z), f2bs((v[7]-mean)*inv*gw.w+bw.w) };
  bf16* o = out + (size_t)row*D_;
  *(short4v*)&o[lane*8]     = r0;
  *(short4v*)&o[lane*8 + 4] = r1;
}

// ---------------- weight fp32[K][N] -> bf16[N][K], ALL layers at once ----------------
__global__ __launch_bounds__(256) void wconv_kernel(
    const float* sq, const float* sk, const float* sv, const float* so,
    const float* tq, const float* tk, const float* tv, const float* to,
    const float* w1, const float* w2, bf16* __restrict__ dst){
  __shared__ float sm[32][33];
  int z = blockIdx.z; int i = z/10, id = z - i*10;
  const size_t wo = (size_t)i*262144, mo = (size_t)i*524288;
  bf16* db = dst + (size_t)i*3145728;
  const float* src; bf16* d; int K, N;
  switch(id){
    case 0: src=sq+wo; d=db+0*262144;  K=512;  N=512;  break;
    case 1: src=sk+wo; d=db+1*262144;  K=512;  N=512;  break;
    case 2: src=sv+wo; d=db+2*262144;  K=512;  N=512;  break;
    case 3: src=so+wo; d=db+3*262144;  K=512;  N=512;  break;
    case 4: src=tq+wo; d=db+4*262144;  K=512;  N=512;  break;
    case 5: src=tk+wo; d=db+5*262144;  K=512;  N=512;  break;
    case 6: src=tv+wo; d=db+6*262144;  K=512;  N=512;  break;
    case 7: src=to+wo; d=db+7*262144;  K=512;  N=512;  break;
    case 8: src=w1+mo; d=db+2097152;   K=512;  N=1024; break;
    default:src=w2+mo; d=db+2621440;   K=1024; N=512;  break;
  }
  int n0 = blockIdx.x<<5, k0 = blockIdx.y<<5;
  if(n0 >= N || k0 >= K) return;
  int tx = threadIdx.x & 31, ty = threadIdx.x >> 5;
  #pragma unroll
  for(int j=0;j<4;j++) sm[ty+j*8][tx] = src[(size_t)(k0+ty+j*8)*N + n0+tx];
  __syncthreads();
  #pragma unroll
  for(int j=0;j<4;j++) d[(size_t)(n0+ty+j*8)*K + k0+tx] = __float2bfloat16(sm[tx][ty+j*8]);
}

// ---------------- bf16 MFMA GEMM, 128x128 tile, BK=64, swizzled (MLP1) ----------------
template<int ACT, bool RES, bool OBF>
__global__ __launch_bounds__(256) void gemm_mfma(
    const bf16* __restrict__ A, const bf16* __restrict__ Wt,
    const float* __restrict__ bias, void* __restrict__ outp,
    const bf16* __restrict__ resid, int K, int N, int c_rpb, int o_rpb){
  __shared__ __align__(16) bf16 As[128*64];
  __shared__ __align__(16) bf16 Bs[128*64];
  const int tid  = threadIdx.x;
  const int lane = tid & 63;
  const int w    = tid >> 6;
  const int row0 = blockIdx.y << 7;
  const int col0 = blockIdx.x << 7;
  const int mb = (w>>1)*64, nb = (w&1)*64;
  size_t ga[4], gb[4];
  #pragma unroll
  for(int r=0;r<4;r++){
    int c = (r*4+w)*64 + lane;
    int rw = c>>3;
    int ks = (c&7) ^ (rw&7);
    ga[r] = (size_t)(row0+rw)*K + (ks<<3);
    gb[r] = (size_t)(col0+rw)*K + (ks<<3);
  }
  f32x4 acc[4][4] = {};
  for(int k0=0;k0<K;k0+=64){
    #pragma unroll
    for(int r=0;r<4;r++){
      gload_lds16(A  + ga[r] + k0, As + (size_t)(r*4+w)*512);
      gload_lds16(Wt + gb[r] + k0, Bs + (size_t)(r*4+w)*512);
    }
    __syncthreads();
    const short8* Av = (const short8*)As;
    const short8* Bv = (const short8*)Bs;
    #pragma unroll
    for(int kk=0;kk<2;kk++){
      const int slot = (lane>>4) + kk*4;
      short8 af[4], bfr[4];
      #pragma unroll
      for(int mi=0;mi<4;mi++){ int rw = mb + mi*16 + (lane&15); af[mi]  = Av[rw*8 + (slot ^ (rw&7))]; }
      #pragma unroll
      for(int ni=0;ni<4;ni++){ int rw = nb + ni*16 + (lane&15); bfr[ni] = Bv[rw*8 + (slot ^ (rw&7))]; }
      #pragma unroll
      for(int mi=0;mi<4;mi++)
        #pragma unroll
        for(int ni=0;ni<4;ni++)
          acc[mi][ni] = __builtin_amdgcn_mfma_f32_16x16x32_bf16(af[mi], bfr[ni], acc[mi][ni], 0,0,0);
    }
    __syncthreads();
  }
  #pragma unroll
  for(int mi=0;mi<4;mi++){
    #pragma unroll
    for(int r=0;r<4;r++){
      int row = row0 + mb + mi*16 + (lane>>4)*4 + r;
      int bb = row / c_rpb;
      size_t orow = (size_t)bb*o_rpb + (row - bb*c_rpb);
      #pragma unroll
      for(int ni=0;ni<4;ni++){
        int col = col0 + nb + ni*16 + (lane&15);
        float v = acc[mi][ni][r] + bias[col];
        if(ACT==1) v = tanhf(v);
        if(RES) v += __bfloat162float(resid[orow*(size_t)N + col]);
        if(OBF) ((bf16*)outp)[orow*(size_t)N + col] = __float2bfloat16(v);
        else    ((float*)outp)[orow*(size_t)N + col] = v;
      }
    }
  }
}

// ---------------- bf16 MFMA GEMM, 64x64 tile, BK=64, swizzled, dbuf (O-proj / MLP2) ----------------
__global__ __launch_bounds__(256) void gemm_mfma64(
    const bf16* __restrict__ A, const bf16* __restrict__ Wt,
    const float* __restrict__ bias, bf16* __restrict__ outp,
    const bf16* __restrict__ resid, int K, int N, int c_rpb, int o_rpb){
  __shared__ __align__(16) bf16 As[2][64*64];
  __shared__ __align__(16) bf16 Bs[2][64*64];
  const int tid  = threadIdx.x;
  const int lane = tid & 63;
  const int w    = tid >> 6;
  const int row0 = blockIdx.y << 6;
  const int col0 = blockIdx.x << 6;
  const int mw = (w>>1)*32, nw = (w&1)*32;
  size_t ga[2], gb[2];
  #pragma unroll
  for(int r=0;r<2;r++){
    int c = (r*4+w)*64 + lane;
    int rw = c>>3;
    int ks = (c&7) ^ (rw&7);
    ga[r] = (size_t)(row0+rw)*K + (ks<<3);
    gb[r] = (size_t)(col0+rw)*K + (ks<<3);
  }
  f32x4 acc[2][2] = {};
  #pragma unroll
  for(int r=0;r<2;r++){
    gload_lds16(A  + ga[r], &As[0][(r*4+w)*512]);
    gload_lds16(Wt + gb[r], &Bs[0][(r*4+w)*512]);
  }
  __syncthreads();
  int cur = 0;
  for(int k0=0;k0<K;k0+=64){
    if(k0+64 < K){
      #pragma unroll
      for(int r=0;r<2;r++){
        gload_lds16(A  + ga[r] + k0+64, &As[cur^1][(r*4+w)*512]);
        gload_lds16(Wt + gb[r] + k0+64, &Bs[cur^1][(r*4+w)*512]);
      }
    }
    const short8* Av = (const short8*)As[cur];
    const short8* Bv = (const short8*)Bs[cur];
    #pragma unroll
    for(int kk=0;kk<2;kk++){
      const int slot = (lane>>4) + kk*4;
      short8 af[2], bfr[2];
      #pragma unroll
      for(int mi=0;mi<2;mi++){ int rw = mw + mi*16 + (lane&15); af[mi]  = Av[rw*8 + (slot ^ (rw&7))]; }
      #pragma unroll
      for(int ni=0;ni<2;ni++){ int rw = nw + ni*16 + (lane&15); bfr[ni] = Bv[rw*8 + (slot ^ (rw&7))]; }
      #pragma unroll
      for(int mi=0;mi<2;mi++)
        #pragma unroll
        for(int ni=0;ni<2;ni++)
          acc[mi][ni] = __builtin_amdgcn_mfma_f32_16x16x32_bf16(af[mi], bfr[ni], acc[mi][ni], 0,0,0);
    }
    __syncthreads();
    cur ^= 1;
  }
  #pragma unroll
  for(int mi=0;mi<2;mi++){
    #pragma unroll
    for(int r=0;r<4;r++){
      int row = row0 + mw + mi*16 + (lane>>4)*4 + r;
      int bb = row / c_rpb;
      size_t orow = (size_t)bb*o_rpb + (row - bb*c_rpb);
      #pragma unroll
      for(int ni=0;ni<2;ni++){
        int col = col0 + nw + ni*16 + (lane&15);
        float v = acc[mi][ni][r] + bias[col];
        v += __bfloat162float(resid[orow*(size_t)N + col]);
        outp[orow*(size_t)N + col] = __float2bfloat16(v);
      }
    }
  }
}

// ---------------- fused QKV GEMM: N=1536, BK=64, swizzled, bf16 outs ----------------
__global__ __launch_bounds__(256) void gemm_qkv(
    const bf16* __restrict__ A, const bf16* __restrict__ Wt,
    const float* __restrict__ bq, const float* __restrict__ bk, const float* __restrict__ bv,
    bf16* __restrict__ Qo, bf16* __restrict__ Ko, bf16* __restrict__ Vo){
  const int K = 512;
  __shared__ __align__(16) bf16 As[128*64];
  __shared__ __align__(16) bf16 Bs[128*64];
  const int tid  = threadIdx.x;
  const int lane = tid & 63;
  const int w    = tid >> 6;
  const int row0 = blockIdx.y << 7;
  const int col0 = blockIdx.x << 7;
  const int mb = (w>>1)*64, nb = (w&1)*64;
  size_t ga[4], gb[4];
  #pragma unroll
  for(int r=0;r<4;r++){
    int c = (r*4+w)*64 + lane;
    int rw = c>>3;
    int ks = (c&7) ^ (rw&7);
    ga[r] = (size_t)(row0+rw)*K + (ks<<3);
    gb[r] = (size_t)(col0+rw)*K + (ks<<3);
  }
  f32x4 acc[4][4] = {};
  for(int k0=0;k0<K;k0+=64){
    #pragma unroll
    for(int r=0;r<4;r++){
      gload_lds16(A  + ga[r] + k0, As + (size_t)(r*4+w)*512);
      gload_lds16(Wt + gb[r] + k0, Bs + (size_t)(r*4+w)*512);
    }
    __syncthreads();
    const short8* Av = (const short8*)As;
    const short8* Bv = (const short8*)Bs;
    #pragma unroll
    for(int kk=0;kk<2;kk++){
      const int slot = (lane>>4) + kk*4;
      short8 af[4], bfr[4];
      #pragma unroll
      for(int mi=0;mi<4;mi++){ int rw = mb + mi*16 + (lane&15); af[mi]  = Av[rw*8 + (slot ^ (rw&7))]; }
      #pragma unroll
      for(int ni=0;ni<4;ni++){ int rw = nb + ni*16 + (lane&15); bfr[ni] = Bv[rw*8 + (slot ^ (rw&7))]; }
      #pragma unroll
      for(int mi=0;mi<4;mi++)
        #pragma unroll
        for(int ni=0;ni<4;ni++)
          acc[mi][ni] = __builtin_amdgcn_mfma_f32_16x16x32_bf16(af[mi], bfr[ni], acc[mi][ni], 0,0,0);
    }
    __syncthreads();
  }
  const int sel = col0 >> 9;
  bf16* outp = (sel==0) ? Qo : (sel==1 ? Ko : Vo);
  const float* bp = (sel==0) ? bq : (sel==1 ? bk : bv);
  const int cb = col0 & 511;
  #pragma unroll
  for(int mi=0;mi<4;mi++){
    #pragma unroll
    for(int r=0;r<4;r++){
      int row = row0 + mb + mi*16 + (lane>>4)*4 + r;
      #pragma unroll
      for(int ni=0;ni<4;ni++){
        int col = cb + nb + ni*16 + (lane&15);
        outp[(size_t)row*512 + col] = __float2bfloat16(acc[mi][ni][r] + bp[col]);
      }
    }
  }
}

// ---------------- spatial 3x3 windowed attention: paired bf16, 2 heads/wave ----------------
__global__ __launch_bounds__(256) void spatial_attn_kernel(
    const bf16* __restrict__ Q, const bf16* __restrict__ K,
    const bf16* __restrict__ V, bf16* __restrict__ O){
  int loc = blockIdx.x;
  int hw = loc & 255;
  int hh = hw >> 4, ww = hw & 15;
  int tid = threadIdx.x, lane = tid & 63, w = tid >> 6;
  int h = w*2 + (lane>>5);
  int j = lane & 31;
  size_t base = (size_t)loc*D_ + h*DH_ + 2*j;
  unsigned uq = *(const unsigned*)&Q[base];
  float q0 = b2f((unsigned short)uq), q1 = b2f((unsigned short)(uq>>16));
  float lg[9]; int nrow[9];
  #pragma unroll
  for(int s=0;s<9;s++){
    int a = s/3 - 1, b2_ = s%3 - 1;
    int nh = hh + a, nw = ww + b2_;
    bool ok = ((unsigned)nh < 16u) && ((unsigned)nw < 16u);
    nrow[s] = ok ? (loc - hw + (nh<<4) + nw) : -1;
    float p = 0.f;
    if(ok){
      unsigned uk = *(const unsigned*)&K[(size_t)nrow[s]*D_ + h*DH_ + 2*j];
      p = q0*b2f((unsigned short)uk) + q1*b2f((unsigned short)(uk>>16));
    }
    #pragma unroll
    for(int o=16;o>0;o>>=1) p += __shfl_xor(p, o, 64);
    lg[s] = ok ? p*0.125f : NEGV;
  }
  float m = lg[0];
  #pragma unroll
  for(int s=1;s<9;s++) m = fmaxf(m, lg[s]);
  float den = 0.f, wv[9];
  #pragma unroll
  for(int s=0;s<9;s++){ wv[s] = __expf(lg[s]-m); den += wv[s]; }
  float inv = 1.f/den;
  float a0 = 0.f, a1 = 0.f;
  #pragma unroll
  for(int s=0;s<9;s++){
    if(nrow[s] >= 0){
      unsigned uv = *(const unsigned*)&V[(size_t)nrow[s]*D_ + h*DH_ + 2*j];
      a0 += wv[s]*b2f((unsigned short)uv);
      a1 += wv[s]*b2f((unsigned short)(uv>>16));
    }
  }
  unsigned up = (unsigned)(unsigned short)f2bs(a0*inv) | ((unsigned)(unsigned short)f2bs(a1*inv) << 16);
  *(unsigned*)&O[base] = up;
}

// ---------------- fused temporal attention: block = (b,hw), 8 waves = 8 heads ----------------
__global__ __launch_bounds__(512) void fused_tattn(
    const bf16* __restrict__ Qb, const bf16* __restrict__ Kb, const bf16* __restrict__ Vb,
    bf16* __restrict__ O, float* __restrict__ kout, float* __restrict__ vout,
    float* __restrict__ ltout, int write_lt){
  __shared__ __align__(16) bf16 Qs[17*520];
  __shared__ __align__(16) bf16 Ks[17*520];
  __shared__ __align__(16) bf16 Vs[17*512];
  __shared__ float Ws[8][17][18];
  const int tid = threadIdx.x, w = tid>>6, lane = tid&63;
  const int hw = blockIdx.x & 255, b = blockIdx.x >> 8;
  const size_t tstr = (size_t)HWL*D_;
  const size_t rb0 = ((size_t)(b*T1_)*HWL + hw)*D_;
  for(int t=w; t<17; t+=8){
    size_t src = rb0 + (size_t)t*tstr + lane*8;
    *(short8*)&Qs[t*520 + lane*8] = *(const short8*)&Qb[src];
    *(short8*)&Ks[t*520 + lane*8] = *(const short8*)&Kb[src];
    *(short8*)&Vs[t*512 + lane*8] = *(const short8*)&Vb[src];
  }
  __syncthreads();
  {
    int i = lane & 31;
    float freq = __expf(-9.210340372f * (float)i * (1.f/32.f));
    bf16* P = (lane < 32) ? Qs : Ks;
    #pragma unroll
    for(int t=0;t<17;t++){
      float sn, cs; __sincosf((float)t*freq, &sn, &cs);
      int idx = t*520 + w*64 + i;
      float x1 = __bfloat162float(P[idx]);
      float x2 = __bfloat162float(P[idx+32]);
      P[idx]    = __float2bfloat16(x1*cs - x2*sn);
      P[idx+32] = __float2bfloat16(x2*cs + x1*sn);
    }
  }
  __syncthreads();
  {
    size_t eb = (((size_t)(b*HWL + hw)*NHH + w)*16)*64 + lane;
    #pragma unroll
    for(int t=0;t<16;t++){
      kout[eb + t*64] = __bfloat162float(Ks[t*520 + w*64 + lane]);
      vout[eb + t*64] = __bfloat162float(Vs[t*512 + w*64 + lane]);
    }
  }
  size_t lb = ((size_t)(b*HWL + hw)*NHH + w)*289;
  for(int p=lane; p<289; p+=64){
    int t = p/17, u = p - t*17;
    float d = 0.f;
    #pragma unroll
    for(int jj=0;jj<8;jj++){
      short8 qq = *(short8*)&Qs[t*520 + w*64 + jj*8];
      short8 kk = *(short8*)&Ks[u*520 + w*64 + jj*8];
      #pragma unroll
      for(int e=0;e<8;e++) d += b2f((unsigned short)qq[e]) * b2f((unsigned short)kk[e]);
    }
    bool masked = (u > t) || (t == 16 && u == 16);
    float lg = masked ? NEGV : d*0.125f;
    Ws[w][t][u] = lg;
    if(write_lt) ltout[lb + t*17 + u] = lg;
  }
  __syncthreads();
  if(lane < 17){
    float m = -1e30f;
    #pragma unroll
    for(int u=0;u<17;u++) m = fmaxf(m, Ws[w][lane][u]);
    float den = 0.f, e[17];
    #pragma unroll
    for(int u=0;u<17;u++){ e[u] = __expf(Ws[w][lane][u]-m); den += e[u]; }
    float inv = 1.f/den;
    #pragma unroll
    for(int u=0;u<17;u++) Ws[w][lane][u] = e[u]*inv;
  }
  __syncthreads();
  float Vr[17];
  #pragma unroll
  for(int u=0;u<17;u++) Vr[u] = __bfloat162float(Vs[u*512 + w*64 + lane]);
  #pragma unroll
  for(int t=0;t<17;t++){
    float acc = 0.f;
    #pragma unroll
    for(int u=0;u<17;u++) acc += Ws[w][t][u]*Vr[u];
    O[rb0 + (size_t)t*tstr + w*64 + lane] = __float2bfloat16(acc);
  }
}

// ---------------- frame-0 spatial mean broadcast, row-coalesced ----------------
__global__ __launch_bounds__(256) void avg_frame0_kernel(bf16* __restrict__ X){
  int b = blockIdx.x >> 3, c = blockIdx.x & 7;
  int ro = threadIdx.x >> 6, dd = threadIdx.x & 63;
  size_t base = ((size_t)(b*T1_)*HWL)*D_ + c*64 + dd;
  float acc = 0.f;
  for(int r=ro; r<256; r+=4) acc += __bfloat162float(X[base + (size_t)r*D_]);
  __shared__ float sm[4][64];
  sm[ro][dd] = acc;
  __syncthreads();
  float v = (sm[0][dd]+sm[1][dd]+sm[2][dd]+sm[3][dd])*(1.f/256.f);
  bf16 bv = __float2bfloat16(v);
  for(int r=ro; r<256; r+=4) X[base + (size_t)r*D_] = bv;
}

extern "C" void kernel_launch(void* const* d_in, const int* in_sizes, int n_in,
                              void* d_out, int out_size, void* d_ws, size_t ws_size,
                              hipStream_t stream){
  const int*   codes = (const int*)  d_in[0];
  const float* emb   = (const float*)d_in[1];
  const float* cls   = (const float*)d_in[2];
  const float* hpos  = (const float*)d_in[3];
  const float* wpos  = (const float*)d_in[4];
  const float* eng   = (const float*)d_in[5];
  const float* enb   = (const float*)d_in[6];
  const float* sn_g  = (const float*)d_in[7];
  const float* sn_b  = (const float*)d_in[8];
  const float* s_wq  = (const float*)d_in[9];
  const float* s_bq  = (const float*)d_in[10];
  const float* s_wk  = (const float*)d_in[11];
  const float* s_bk  = (const float*)d_in[12];
  const float* s_wv  = (const float*)d_in[13];
  const float* s_bv  = (const float*)d_in[14];
  const float* s_wo  = (const float*)d_in[15];
  const float* s_bo  = (const float*)d_in[16];
  const float* tn_g  = (const float*)d_in[17];
  const float* tn_b  = (const float*)d_in[18];
  const float* t_wq  = (const float*)d_in[19];
  const float* t_bq  = (const float*)d_in[20];
  const float* t_wk  = (const float*)d_in[21];
  const float* t_bk  = (const float*)d_in[22];
  const float* t_wv  = (const float*)d_in[23];
  const float* t_bv  = (const float*)d_in[24];
  const float* t_wo  = (const float*)d_in[25];
  const float* t_bo  = (const float*)d_in[26];
  const float* mn_g  = (const float*)d_in[27];
  const float* mn_b  = (const float*)d_in[28];
  const float* mw1   = (const float*)d_in[29];
  const float* mb1   = (const float*)d_in[30];
  const float* mw2   = (const float*)d_in[31];
  const float* mb2   = (const float*)d_in[32];
  const float* fn_g  = (const float*)d_in[33];
  const float* fn_b  = (const float*)d_in[34];

  const size_t NX = 4456448;               // B*T1*HW*D
  bf16* Xb  = (bf16*)d_ws;                 // residual stream, bf16
  bf16* XNb = Xb  + NX;
  bf16* Qb  = XNb + NX;
  bf16* Kb  = Qb  + NX;
  bf16* Vb  = Kb  + NX;
  bf16* Wt  = Vb  + NX;                    // 6 layers x 3,145,728 bf16
  bf16* HIDb= Qb;                          // [8704][1024] bf16, aliases Qb+Kb

  float* out0 = (float*)d_out;
  float* out1 = out0 + NX;
  float* out2 = out1 + 1183744;
  float* out3 = out2 + 25165824;

  const int RS = B__*T_*HWL;           // 8192
  const int RT = B__*T1_*HWL;          // 8704
  dim3 gQs(12, 64);
  dim3 gQt(12, 68);
  dim3 g64s(8, 128);                   // N=512, M=8192 (64^2)
  dim3 g64t(8, 136);                   // N=512, M=8704 (64^2)
  dim3 gM1(8, 68);                     // MLP1: N=1024, 128^2 tiles
  dim3 wcg(32, 32, 60);

  embed_ln_kernel<<<RT/4, 256, 0, stream>>>(codes, emb, cls, hpos, wpos, eng, enb, Xb);
  wconv_kernel<<<wcg,256,0,stream>>>(s_wq, s_wk, s_wv, s_wo, t_wq, t_wk, t_wv, t_wo, mw1, mw2, Wt);

  for(int i=0;i<6;i++){
    bf16* Wl = Wt + (size_t)i*3145728;
    // ---- spatial windowed attention ----
    ln_bf_kernel<<<RS/4,256,0,stream>>>(Xb, XNb, sn_g+i*D_, sn_b+i*D_, T_*HWL, T1_*HWL);
    gemm_qkv<<<gQs,256,0,stream>>>(XNb, Wl, s_bq+i*D_, s_bk+i*D_, s_bv+i*D_, Qb, Kb, Vb);
    spatial_attn_kernel<<<RS,256,0,stream>>>(Qb, Kb, Vb, XNb);
    gemm_mfma64<<<g64s,256,0,stream>>>(XNb, Wl+3*262144, s_bo+i*D_, Xb, Xb, 512, 512, T_*HWL, T1_*HWL);
    // ---- temporal RoPE causal attention (fused) ----
    ln_bf_kernel<<<RT/4,256,0,stream>>>(Xb, XNb, tn_g+i*D_, tn_b+i*D_, T1_*HWL, T1_*HWL);
    gemm_qkv<<<gQt,256,0,stream>>>(XNb, Wl+4*262144, t_bq+i*D_, t_bk+i*D_, t_bv+i*D_, Qb, Kb, Vb);
    fused_tattn<<<512,512,0,stream>>>(Qb, Kb, Vb, XNb,
                                      out2+(size_t)i*4194304, out3+(size_t)i*4194304,
                                      out1, (i==5)?1:0);
    gemm_mfma64<<<g64t,256,0,stream>>>(XNb, Wl+7*262144, t_bo+i*D_, Xb, Xb, 512, 512, RT, RT);
    avg_frame0_kernel<<<16,256,0,stream>>>(Xb);
    // ---- MLP ----
    ln_bf_kernel<<<RT/4,256,0,stream>>>(Xb, XNb, mn_g+i*D_, mn_b+i*D_, T1_*HWL, T1_*HWL);
    gemm_mfma<1,false,true ><<<gM1,256,0,stream>>>(XNb, Wl+2097152, mb1+i*1024, HIDb, nullptr, 512, 1024, RT, RT);
    gemm_mfma64<<<g64t,256,0,stream>>>(HIDb, Wl+2621440, mb2+i*D_, Xb, Xb, 1024, 512, RT, RT);
  }
  ln_kernel<<<RT/4,256,0,stream>>>(Xb, out0, fn_g, fn_b, T1_*HWL, T1_*HWL);
}

// Round 12
// 1294.964 us; speedup vs baseline: 1.1767x; 1.0706x over previous
//
#include <hip/hip_runtime.h>
#include <hip/hip_bf16.h>
#include <math.h>

#define D_    512
#define NHH   8
#define DH_   64
#define T_    16
#define T1_   17
#define HWL   256
#define B__   2
#define NEGV  -1e9f

typedef __attribute__((ext_vector_type(8))) short short8;
typedef __attribute__((ext_vector_type(4))) short short4v;
typedef __attribute__((ext_vector_type(4))) float f32x4;
typedef __hip_bfloat16 bf16;

__device__ inline float wave_sum(float v){
  #pragma unroll
  for(int o=32;o>0;o>>=1) v += __shfl_xor(v,o,64);
  return v;
}
__device__ inline float b2f(unsigned short s){
  unsigned u = ((unsigned)s)<<16; float f; __builtin_memcpy(&f,&u,4); return f;
}
__device__ inline short f2bs(float f){
  bf16 h = __float2bfloat16(f); short s; __builtin_memcpy(&s,&h,2); return s;
}
__device__ inline void gload_lds16(const void* g, void* l){
  __builtin_amdgcn_global_load_lds((const __attribute__((address_space(1))) void*)g,
                                   (__attribute__((address_space(3))) void*)l, 16, 0, 0);
}

// ---------------- embedding + LN, bf16 out ----------------
__global__ __launch_bounds__(256) void embed_ln_kernel(
    const int* __restrict__ codes, const float* __restrict__ emb,
    const float* __restrict__ cls, const float* __restrict__ hpos,
    const float* __restrict__ wpos, const float* __restrict__ g,
    const float* __restrict__ bta, bf16* __restrict__ X){
  int row  = blockIdx.x*4 + (threadIdx.x>>6);
  int lane = threadIdx.x & 63;
  int hw = row % HWL; int bt = row / HWL; int t = bt % T1_; int bb = bt / T1_;
  float v[8];
  if(t < T_){
    int code = codes[(bb*T_ + t)*HWL + hw];
    const float4* ep = (const float4*)(emb  + (size_t)code*D_);
    const float4* hp = (const float4*)(hpos + (size_t)(hw & 15)*D_);
    const float4* wp = (const float4*)(wpos + (size_t)(hw >> 4)*D_);
    float4 a0=ep[lane*2], a1=ep[lane*2+1];
    float4 h0=hp[lane*2], h1=hp[lane*2+1];
    float4 w0=wp[lane*2], w1=wp[lane*2+1];
    v[0]=a0.x+h0.x+w0.x; v[1]=a0.y+h0.y+w0.y; v[2]=a0.z+h0.z+w0.z; v[3]=a0.w+h0.w+w0.w;
    v[4]=a1.x+h1.x+w1.x; v[5]=a1.y+h1.y+w1.y; v[6]=a1.z+h1.z+w1.z; v[7]=a1.w+h1.w+w1.w;
  } else {
    const float4* cp = (const float4*)cls;
    float4 c0=cp[lane*2], c1=cp[lane*2+1];
    v[0]=c0.x; v[1]=c0.y; v[2]=c0.z; v[3]=c0.w; v[4]=c1.x; v[5]=c1.y; v[6]=c1.z; v[7]=c1.w;
  }
  float s=0;
  #pragma unroll
  for(int j=0;j<8;j++) s += v[j];
  s = wave_sum(s);
  float mean = s*(1.f/512.f);
  float s2=0;
  #pragma unroll
  for(int j=0;j<8;j++){ float d0=v[j]-mean; s2 += d0*d0; }
  s2 = wave_sum(s2);
  float inv = rsqrtf(s2*(1.f/512.f) + 1e-5f);
  const float4* g4 = (const float4*)g; const float4* b4 = (const float4*)bta;
  float4 gv=g4[lane*2], gw=g4[lane*2+1], bv=b4[lane*2], bw=b4[lane*2+1];
  short4v r0 = { f2bs((v[0]-mean)*inv*gv.x+bv.x), f2bs((v[1]-mean)*inv*gv.y+bv.y),
                 f2bs((v[2]-mean)*inv*gv.z+bv.z), f2bs((v[3]-mean)*inv*gv.w+bv.w) };
  short4v r1 = { f2bs((v[4]-mean)*inv*gw.x+bw.x), f2bs((v[5]-mean)*inv*gw.y+bw.y),
                 f2bs((v[6]-mean)*inv*gw.z+bw.z), f2bs((v[7]-mean)*inv*gw.w+bw.w) };
  bf16* o = X + (size_t)row*D_;
  *(short4v*)&o[lane*8]     = r0;
  *(short4v*)&o[lane*8 + 4] = r1;
}

// ---------------- LayerNorm, bf16 in -> fp32 out (final) ----------------
__global__ __launch_bounds__(256) void ln_kernel(
    const bf16* __restrict__ in, float* __restrict__ out,
    const float* __restrict__ g, const float* __restrict__ bta,
    int c_rpb, int s_rpb){
  int row  = blockIdx.x*4 + (threadIdx.x>>6);
  int lane = threadIdx.x & 63;
  int bb = row / c_rpb; int rem = row - bb*c_rpb;
  short8 vv = *(const short8*)(in + ((size_t)bb*s_rpb + rem)*D_ + lane*8);
  float v[8]; float s=0;
  #pragma unroll
  for(int j=0;j<8;j++){ v[j] = b2f((unsigned short)vv[j]); s += v[j]; }
  s = wave_sum(s);
  float mean = s*(1.f/512.f);
  float s2=0;
  #pragma unroll
  for(int j=0;j<8;j++){ float d0=v[j]-mean; s2 += d0*d0; }
  s2 = wave_sum(s2);
  float inv = rsqrtf(s2*(1.f/512.f) + 1e-5f);
  const float4* g4 = (const float4*)g; const float4* b4 = (const float4*)bta;
  float4 gv=g4[lane*2], gw=g4[lane*2+1], bv=b4[lane*2], bw=b4[lane*2+1];
  float4 o0 = { (v[0]-mean)*inv*gv.x+bv.x, (v[1]-mean)*inv*gv.y+bv.y,
                (v[2]-mean)*inv*gv.z+bv.z, (v[3]-mean)*inv*gv.w+bv.w };
  float4 o1 = { (v[4]-mean)*inv*gw.x+bw.x, (v[5]-mean)*inv*gw.y+bw.y,
                (v[6]-mean)*inv*gw.z+bw.z, (v[7]-mean)*inv*gw.w+bw.w };
  float* o = out + (size_t)row*D_;
  *(float4*)&o[lane*8]     = o0;
  *(float4*)&o[lane*8 + 4] = o1;
}

// ---------------- LayerNorm, bf16 in -> bf16 out ----------------
__global__ __launch_bounds__(256) void ln_bf_kernel(
    const bf16* __restrict__ in, bf16* __restrict__ out,
    const float* __restrict__ g, const float* __restrict__ bta,
    int c_rpb, int s_rpb){
  int row  = blockIdx.x*4 + (threadIdx.x>>6);
  int lane = threadIdx.x & 63;
  int bb = row / c_rpb; int rem = row - bb*c_rpb;
  short8 vv = *(const short8*)(in + ((size_t)bb*s_rpb + rem)*D_ + lane*8);
  float v[8]; float s=0;
  #pragma unroll
  for(int j=0;j<8;j++){ v[j] = b2f((unsigned short)vv[j]); s += v[j]; }
  s = wave_sum(s);
  float mean = s*(1.f/512.f);
  float s2=0;
  #pragma unroll
  for(int j=0;j<8;j++){ float d0=v[j]-mean; s2 += d0*d0; }
  s2 = wave_sum(s2);
  float inv = rsqrtf(s2*(1.f/512.f) + 1e-5f);
  const float4* g4 = (const float4*)g; const float4* b4 = (const float4*)bta;
  float4 gv=g4[lane*2], gw=g4[lane*2+1], bv=b4[lane*2], bw=b4[lane*2+1];
  short4v r0 = { f2bs((v[0]-mean)*inv*gv.x+bv.x), f2bs((v[1]-mean)*inv*gv.y+bv.y),
                 f2bs((v[2]-mean)*inv*gv.z+bv.z), f2bs((v[3]-mean)*inv*gv.w+bv.w) };
  short4v r1 = { f2bs((v[4]-mean)*inv*gw.x+bw.x), f2bs((v[5]-mean)*inv*gw.y+bw.y),
                 f2bs((v[6]-mean)*inv*gw.z+bw.z), f2bs((v[7]-mean)*inv*gw.w+bw.w) };
  bf16* o = out + (size_t)row*D_;
  *(short4v*)&o[lane*8]     = r0;
  *(short4v*)&o[lane*8 + 4] = r1;
}

// ---------------- weight fp32[K][N] -> bf16[N][K], ALL layers at once ----------------
__global__ __launch_bounds__(256) void wconv_kernel(
    const float* sq, const float* sk, const float* sv, const float* so,
    const float* tq, const float* tk, const float* tv, const float* to,
    const float* w1, const float* w2, bf16* __restrict__ dst){
  __shared__ float sm[32][33];
  int z = blockIdx.z; int i = z/10, id = z - i*10;
  const size_t wo = (size_t)i*262144, mo = (size_t)i*524288;
  bf16* db = dst + (size_t)i*3145728;
  const float* src; bf16* d; int K, N;
  switch(id){
    case 0: src=sq+wo; d=db+0*262144;  K=512;  N=512;  break;
    case 1: src=sk+wo; d=db+1*262144;  K=512;  N=512;  break;
    case 2: src=sv+wo; d=db+2*262144;  K=512;  N=512;  break;
    case 3: src=so+wo; d=db+3*262144;  K=512;  N=512;  break;
    case 4: src=tq+wo; d=db+4*262144;  K=512;  N=512;  break;
    case 5: src=tk+wo; d=db+5*262144;  K=512;  N=512;  break;
    case 6: src=tv+wo; d=db+6*262144;  K=512;  N=512;  break;
    case 7: src=to+wo; d=db+7*262144;  K=512;  N=512;  break;
    case 8: src=w1+mo; d=db+2097152;   K=512;  N=1024; break;
    default:src=w2+mo; d=db+2621440;   K=1024; N=512;  break;
  }
  int n0 = blockIdx.x<<5, k0 = blockIdx.y<<5;
  if(n0 >= N || k0 >= K) return;
  int tx = threadIdx.x & 31, ty = threadIdx.x >> 5;
  #pragma unroll
  for(int j=0;j<4;j++) sm[ty+j*8][tx] = src[(size_t)(k0+ty+j*8)*N + n0+tx];
  __syncthreads();
  #pragma unroll
  for(int j=0;j<4;j++) d[(size_t)(n0+ty+j*8)*K + k0+tx] = __float2bfloat16(sm[tx][ty+j*8]);
}

// ---------------- bf16 MFMA GEMM, 128x128 tile, BK=64, swizzled (MLP1) ----------------
template<int ACT, bool RES, bool OBF>
__global__ __launch_bounds__(256) void gemm_mfma(
    const bf16* __restrict__ A, const bf16* __restrict__ Wt,
    const float* __restrict__ bias, void* __restrict__ outp,
    const bf16* __restrict__ resid, int K, int N, int c_rpb, int o_rpb){
  __shared__ __align__(16) bf16 As[128*64];
  __shared__ __align__(16) bf16 Bs[128*64];
  const int tid  = threadIdx.x;
  const int lane = tid & 63;
  const int w    = tid >> 6;
  const int row0 = blockIdx.y << 7;
  const int col0 = blockIdx.x << 7;
  const int mb = (w>>1)*64, nb = (w&1)*64;
  size_t ga[4], gb[4];
  #pragma unroll
  for(int r=0;r<4;r++){
    int c = (r*4+w)*64 + lane;
    int rw = c>>3;
    int ks = (c&7) ^ (rw&7);
    ga[r] = (size_t)(row0+rw)*K + (ks<<3);
    gb[r] = (size_t)(col0+rw)*K + (ks<<3);
  }
  f32x4 acc[4][4] = {};
  for(int k0=0;k0<K;k0+=64){
    #pragma unroll
    for(int r=0;r<4;r++){
      gload_lds16(A  + ga[r] + k0, As + (size_t)(r*4+w)*512);
      gload_lds16(Wt + gb[r] + k0, Bs + (size_t)(r*4+w)*512);
    }
    __syncthreads();
    const short8* Av = (const short8*)As;
    const short8* Bv = (const short8*)Bs;
    #pragma unroll
    for(int kk=0;kk<2;kk++){
      const int slot = (lane>>4) + kk*4;
      short8 af[4], bfr[4];
      #pragma unroll
      for(int mi=0;mi<4;mi++){ int rw = mb + mi*16 + (lane&15); af[mi]  = Av[rw*8 + (slot ^ (rw&7))]; }
      #pragma unroll
      for(int ni=0;ni<4;ni++){ int rw = nb + ni*16 + (lane&15); bfr[ni] = Bv[rw*8 + (slot ^ (rw&7))]; }
      #pragma unroll
      for(int mi=0;mi<4;mi++)
        #pragma unroll
        for(int ni=0;ni<4;ni++)
          acc[mi][ni] = __builtin_amdgcn_mfma_f32_16x16x32_bf16(af[mi], bfr[ni], acc[mi][ni], 0,0,0);
    }
    __syncthreads();
  }
  #pragma unroll
  for(int mi=0;mi<4;mi++){
    #pragma unroll
    for(int r=0;r<4;r++){
      int row = row0 + mb + mi*16 + (lane>>4)*4 + r;
      int bb = row / c_rpb;
      size_t orow = (size_t)bb*o_rpb + (row - bb*c_rpb);
      #pragma unroll
      for(int ni=0;ni<4;ni++){
        int col = col0 + nb + ni*16 + (lane&15);
        float v = acc[mi][ni][r] + bias[col];
        if(ACT==1) v = tanhf(v);
        if(RES) v += __bfloat162float(resid[orow*(size_t)N + col]);
        if(OBF) ((bf16*)outp)[orow*(size_t)N + col] = __float2bfloat16(v);
        else    ((float*)outp)[orow*(size_t)N + col] = v;
      }
    }
  }
}

// ---------------- bf16 MFMA GEMM, 64x64 tile, BK=64, swizzled, dbuf (O-proj / MLP2) ----------------
__global__ __launch_bounds__(256) void gemm_mfma64(
    const bf16* __restrict__ A, const bf16* __restrict__ Wt,
    const float* __restrict__ bias, bf16* __restrict__ outp,
    const bf16* __restrict__ resid, int K, int N, int c_rpb, int o_rpb){
  __shared__ __align__(16) bf16 As[2][64*64];
  __shared__ __align__(16) bf16 Bs[2][64*64];
  const int tid  = threadIdx.x;
  const int lane = tid & 63;
  const int w    = tid >> 6;
  const int row0 = blockIdx.y << 6;
  const int col0 = blockIdx.x << 6;
  const int mw = (w>>1)*32, nw = (w&1)*32;
  size_t ga[2], gb[2];
  #pragma unroll
  for(int r=0;r<2;r++){
    int c = (r*4+w)*64 + lane;
    int rw = c>>3;
    int ks = (c&7) ^ (rw&7);
    ga[r] = (size_t)(row0+rw)*K + (ks<<3);
    gb[r] = (size_t)(col0+rw)*K + (ks<<3);
  }
  f32x4 acc[2][2] = {};
  #pragma unroll
  for(int r=0;r<2;r++){
    gload_lds16(A  + ga[r], &As[0][(r*4+w)*512]);
    gload_lds16(Wt + gb[r], &Bs[0][(r*4+w)*512]);
  }
  __syncthreads();
  int cur = 0;
  for(int k0=0;k0<K;k0+=64){
    if(k0+64 < K){
      #pragma unroll
      for(int r=0;r<2;r++){
        gload_lds16(A  + ga[r] + k0+64, &As[cur^1][(r*4+w)*512]);
        gload_lds16(Wt + gb[r] + k0+64, &Bs[cur^1][(r*4+w)*512]);
      }
    }
    const short8* Av = (const short8*)As[cur];
    const short8* Bv = (const short8*)Bs[cur];
    #pragma unroll
    for(int kk=0;kk<2;kk++){
      const int slot = (lane>>4) + kk*4;
      short8 af[2], bfr[2];
      #pragma unroll
      for(int mi=0;mi<2;mi++){ int rw = mw + mi*16 + (lane&15); af[mi]  = Av[rw*8 + (slot ^ (rw&7))]; }
      #pragma unroll
      for(int ni=0;ni<2;ni++){ int rw = nw + ni*16 + (lane&15); bfr[ni] = Bv[rw*8 + (slot ^ (rw&7))]; }
      #pragma unroll
      for(int mi=0;mi<2;mi++)
        #pragma unroll
        for(int ni=0;ni<2;ni++)
          acc[mi][ni] = __builtin_amdgcn_mfma_f32_16x16x32_bf16(af[mi], bfr[ni], acc[mi][ni], 0,0,0);
    }
    __syncthreads();
    cur ^= 1;
  }
  #pragma unroll
  for(int mi=0;mi<2;mi++){
    #pragma unroll
    for(int r=0;r<4;r++){
      int row = row0 + mw + mi*16 + (lane>>4)*4 + r;
      int bb = row / c_rpb;
      size_t orow = (size_t)bb*o_rpb + (row - bb*c_rpb);
      #pragma unroll
      for(int ni=0;ni<2;ni++){
        int col = col0 + nw + ni*16 + (lane&15);
        float v = acc[mi][ni][r] + bias[col];
        v += __bfloat162float(resid[orow*(size_t)N + col]);
        outp[orow*(size_t)N + col] = __float2bfloat16(v);
      }
    }
  }
}

// ---------------- fused QKV GEMM: N=1536, BK=64, swizzled, bf16 outs ----------------
__global__ __launch_bounds__(256) void gemm_qkv(
    const bf16* __restrict__ A, const bf16* __restrict__ Wt,
    const float* __restrict__ bq, const float* __restrict__ bk, const float* __restrict__ bv,
    bf16* __restrict__ Qo, bf16* __restrict__ Ko, bf16* __restrict__ Vo){
  const int K = 512;
  __shared__ __align__(16) bf16 As[128*64];
  __shared__ __align__(16) bf16 Bs[128*64];
  const int tid  = threadIdx.x;
  const int lane = tid & 63;
  const int w    = tid >> 6;
  const int row0 = blockIdx.y << 7;
  const int col0 = blockIdx.x << 7;
  const int mb = (w>>1)*64, nb = (w&1)*64;
  size_t ga[4], gb[4];
  #pragma unroll
  for(int r=0;r<4;r++){
    int c = (r*4+w)*64 + lane;
    int rw = c>>3;
    int ks = (c&7) ^ (rw&7);
    ga[r] = (size_t)(row0+rw)*K + (ks<<3);
    gb[r] = (size_t)(col0+rw)*K + (ks<<3);
  }
  f32x4 acc[4][4] = {};
  for(int k0=0;k0<K;k0+=64){
    #pragma unroll
    for(int r=0;r<4;r++){
      gload_lds16(A  + ga[r] + k0, As + (size_t)(r*4+w)*512);
      gload_lds16(Wt + gb[r] + k0, Bs + (size_t)(r*4+w)*512);
    }
    __syncthreads();
    const short8* Av = (const short8*)As;
    const short8* Bv = (const short8*)Bs;
    #pragma unroll
    for(int kk=0;kk<2;kk++){
      const int slot = (lane>>4) + kk*4;
      short8 af[4], bfr[4];
      #pragma unroll
      for(int mi=0;mi<4;mi++){ int rw = mb + mi*16 + (lane&15); af[mi]  = Av[rw*8 + (slot ^ (rw&7))]; }
      #pragma unroll
      for(int ni=0;ni<4;ni++){ int rw = nb + ni*16 + (lane&15); bfr[ni] = Bv[rw*8 + (slot ^ (rw&7))]; }
      #pragma unroll
      for(int mi=0;mi<4;mi++)
        #pragma unroll
        for(int ni=0;ni<4;ni++)
          acc[mi][ni] = __builtin_amdgcn_mfma_f32_16x16x32_bf16(af[mi], bfr[ni], acc[mi][ni], 0,0,0);
    }
    __syncthreads();
  }
  const int sel = col0 >> 9;
  bf16* outp = (sel==0) ? Qo : (sel==1 ? Ko : Vo);
  const float* bp = (sel==0) ? bq : (sel==1 ? bk : bv);
  const int cb = col0 & 511;
  #pragma unroll
  for(int mi=0;mi<4;mi++){
    #pragma unroll
    for(int r=0;r<4;r++){
      int row = row0 + mb + mi*16 + (lane>>4)*4 + r;
      #pragma unroll
      for(int ni=0;ni<4;ni++){
        int col = cb + nb + ni*16 + (lane&15);
        outp[(size_t)row*512 + col] = __float2bfloat16(acc[mi][ni][r] + bp[col]);
      }
    }
  }
}

// ---------------- spatial 3x3 windowed attention v2: block=(frame,head), LDS-tiled ----------------
// Q/K/V: [8192][512] compact. Thread = one location; zero cross-lane ops.
// LDS layout per matrix: [row 0..255][slot 0..7], 16B chunks, slot stored at (slot ^ (row&7)).
__global__ __launch_bounds__(256) void spatial_attn_kernel(
    const bf16* __restrict__ Q, const bf16* __restrict__ K,
    const bf16* __restrict__ V, bf16* __restrict__ O){
  __shared__ __align__(16) bf16 Qs[256*64];   // 32 KB (reused for output)
  __shared__ __align__(16) bf16 Ks[256*64];
  __shared__ __align__(16) bf16 Vs[256*64];
  const int f = blockIdx.x >> 3, h = blockIdx.x & 7;
  const int tid = threadIdx.x;
  const size_t base = ((size_t)f*256)*512 + h*64;
  // stage: chunk c -> row c>>3, stored slot c&7; source slot pre-swizzled
  #pragma unroll
  for(int j=0;j<8;j++){
    int c = tid + j*256;
    int r = c >> 3, sl = c & 7;
    size_t src = base + (size_t)r*512 + ((sl ^ (r&7))<<3);
    gload_lds16(Q + src, Qs + (size_t)c*8);
    gload_lds16(K + src, Ks + (size_t)c*8);
    gload_lds16(V + src, Vs + (size_t)c*8);
  }
  __syncthreads();
  const int hh = tid >> 4, ww = tid & 15;
  const short8* Qv = (const short8*)Qs;
  const short8* Kv = (const short8*)Ks;
  const short8* Vv = (const short8*)Vs;
  // own q into registers (swizzled read)
  short8 q[8];
  #pragma unroll
  for(int j=0;j<8;j++) q[j] = Qv[tid*8 + (j ^ (tid&7))];
  // logits
  float lg[9]; int nrow[9];
  #pragma unroll
  for(int s=0;s<9;s++){
    int a = s/3 - 1, b2_ = s%3 - 1;
    int nh = hh + a, nw = ww + b2_;
    bool ok = ((unsigned)nh < 16u) && ((unsigned)nw < 16u);
    int nr = (nh<<4) + nw;
    nrow[s] = ok ? nr : -1;
    float d = 0.f;
    if(ok){
      #pragma unroll
      for(int j=0;j<8;j++){
        short8 kk = Kv[nr*8 + (j ^ (nr&7))];
        #pragma unroll
        for(int e=0;e<8;e++) d += b2f((unsigned short)q[j][e]) * b2f((unsigned short)kk[e]);
      }
    }
    lg[s] = ok ? d*0.125f : NEGV;
  }
  // softmax (fully in registers)
  float m = lg[0];
  #pragma unroll
  for(int s=1;s<9;s++) m = fmaxf(m, lg[s]);
  float den = 0.f, wv[9];
  #pragma unroll
  for(int s=0;s<9;s++){ wv[s] = __expf(lg[s]-m); den += wv[s]; }
  float inv = 1.f/den;
  #pragma unroll
  for(int s=0;s<9;s++) wv[s] *= inv;
  // AV, chunk by chunk; stage output in Qs (own row only -> no hazard)
  #pragma unroll
  for(int j=0;j<8;j++){
    float acc8[8] = {};
    #pragma unroll
    for(int s=0;s<9;s++){
      if(nrow[s] >= 0){
        short8 vvv = Vv[nrow[s]*8 + (j ^ (nrow[s]&7))];
        #pragma unroll
        for(int e=0;e<8;e++) acc8[e] += wv[s]*b2f((unsigned short)vvv[e]);
      }
    }
    short8 ovec;
    #pragma unroll
    for(int e=0;e<8;e++) ovec[e] = f2bs(acc8[e]);
    *(short8*)&Qs[(tid*8 + (j ^ (tid&7)))*8] = ovec;
  }
  __syncthreads();
  // coalesced write-out (swizzled LDS read, linear global write)
  #pragma unroll
  for(int j=0;j<8;j++){
    int c = tid + j*256;
    int r = c >> 3, sl = c & 7;
    short8 ovec = Qv[r*8 + ((sl ^ (r&7)))];
    *(short8*)&O[base + (size_t)r*512 + (sl<<3)] = ovec;
  }
}

// ---------------- fused temporal attention: block = (b,hw), 8 waves = 8 heads ----------------
__global__ __launch_bounds__(512) void fused_tattn(
    const bf16* __restrict__ Qb, const bf16* __restrict__ Kb, const bf16* __restrict__ Vb,
    bf16* __restrict__ O, float* __restrict__ kout, float* __restrict__ vout,
    float* __restrict__ ltout, int write_lt){
  __shared__ __align__(16) bf16 Qs[17*520];
  __shared__ __align__(16) bf16 Ks[17*520];
  __shared__ __align__(16) bf16 Vs[17*512];
  __shared__ float Ws[8][17][18];
  const int tid = threadIdx.x, w = tid>>6, lane = tid&63;
  const int hw = blockIdx.x & 255, b = blockIdx.x >> 8;
  const size_t tstr = (size_t)HWL*D_;
  const size_t rb0 = ((size_t)(b*T1_)*HWL + hw)*D_;
  for(int t=w; t<17; t+=8){
    size_t src = rb0 + (size_t)t*tstr + lane*8;
    *(short8*)&Qs[t*520 + lane*8] = *(const short8*)&Qb[src];
    *(short8*)&Ks[t*520 + lane*8] = *(const short8*)&Kb[src];
    *(short8*)&Vs[t*512 + lane*8] = *(const short8*)&Vb[src];
  }
  __syncthreads();
  {
    int i = lane & 31;
    float freq = __expf(-9.210340372f * (float)i * (1.f/32.f));
    bf16* P = (lane < 32) ? Qs : Ks;
    #pragma unroll
    for(int t=0;t<17;t++){
      float sn, cs; __sincosf((float)t*freq, &sn, &cs);
      int idx = t*520 + w*64 + i;
      float x1 = __bfloat162float(P[idx]);
      float x2 = __bfloat162float(P[idx+32]);
      P[idx]    = __float2bfloat16(x1*cs - x2*sn);
      P[idx+32] = __float2bfloat16(x2*cs + x1*sn);
    }
  }
  __syncthreads();
  {
    size_t eb = (((size_t)(b*HWL + hw)*NHH + w)*16)*64 + lane;
    #pragma unroll
    for(int t=0;t<16;t++){
      kout[eb + t*64] = __bfloat162float(Ks[t*520 + w*64 + lane]);
      vout[eb + t*64] = __bfloat162float(Vs[t*512 + w*64 + lane]);
    }
  }
  size_t lb = ((size_t)(b*HWL + hw)*NHH + w)*289;
  for(int p=lane; p<289; p+=64){
    int t = p/17, u = p - t*17;
    float d = 0.f;
    #pragma unroll
    for(int jj=0;jj<8;jj++){
      short8 qq = *(short8*)&Qs[t*520 + w*64 + jj*8];
      short8 kk = *(short8*)&Ks[u*520 + w*64 + jj*8];
      #pragma unroll
      for(int e=0;e<8;e++) d += b2f((unsigned short)qq[e]) * b2f((unsigned short)kk[e]);
    }
    bool masked = (u > t) || (t == 16 && u == 16);
    float lg = masked ? NEGV : d*0.125f;
    Ws[w][t][u] = lg;
    if(write_lt) ltout[lb + t*17 + u] = lg;
  }
  __syncthreads();
  if(lane < 17){
    float m = -1e30f;
    #pragma unroll
    for(int u=0;u<17;u++) m = fmaxf(m, Ws[w][lane][u]);
    float den = 0.f, e[17];
    #pragma unroll
    for(int u=0;u<17;u++){ e[u] = __expf(Ws[w][lane][u]-m); den += e[u]; }
    float inv = 1.f/den;
    #pragma unroll
    for(int u=0;u<17;u++) Ws[w][lane][u] = e[u]*inv;
  }
  __syncthreads();
  float Vr[17];
  #pragma unroll
  for(int u=0;u<17;u++) Vr[u] = __bfloat162float(Vs[u*512 + w*64 + lane]);
  #pragma unroll
  for(int t=0;t<17;t++){
    float acc = 0.f;
    #pragma unroll
    for(int u=0;u<17;u++) acc += Ws[w][t][u]*Vr[u];
    O[rb0 + (size_t)t*tstr + w*64 + lane] = __float2bfloat16(acc);
  }
}

// ---------------- frame-0 spatial mean broadcast, row-coalesced ----------------
__global__ __launch_bounds__(256) void avg_frame0_kernel(bf16* __restrict__ X){
  int b = blockIdx.x >> 3, c = blockIdx.x & 7;
  int ro = threadIdx.x >> 6, dd = threadIdx.x & 63;
  size_t base = ((size_t)(b*T1_)*HWL)*D_ + c*64 + dd;
  float acc = 0.f;
  for(int r=ro; r<256; r+=4) acc += __bfloat162float(X[base + (size_t)r*D_]);
  __shared__ float sm[4][64];
  sm[ro][dd] = acc;
  __syncthreads();
  float v = (sm[0][dd]+sm[1][dd]+sm[2][dd]+sm[3][dd])*(1.f/256.f);
  bf16 bv = __float2bfloat16(v);
  for(int r=ro; r<256; r+=4) X[base + (size_t)r*D_] = bv;
}

extern "C" void kernel_launch(void* const* d_in, const int* in_sizes, int n_in,
                              void* d_out, int out_size, void* d_ws, size_t ws_size,
                              hipStream_t stream){
  const int*   codes = (const int*)  d_in[0];
  const float* emb   = (const float*)d_in[1];
  const float* cls   = (const float*)d_in[2];
  const float* hpos  = (const float*)d_in[3];
  const float* wpos  = (const float*)d_in[4];
  const float* eng   = (const float*)d_in[5];
  const float* enb   = (const float*)d_in[6];
  const float* sn_g  = (const float*)d_in[7];
  const float* sn_b  = (const float*)d_in[8];
  const float* s_wq  = (const float*)d_in[9];
  const float* s_bq  = (const float*)d_in[10];
  const float* s_wk  = (const float*)d_in[11];
  const float* s_bk  = (const float*)d_in[12];
  const float* s_wv  = (const float*)d_in[13];
  const float* s_bv  = (const float*)d_in[14];
  const float* s_wo  = (const float*)d_in[15];
  const float* s_bo  = (const float*)d_in[16];
  const float* tn_g  = (const float*)d_in[17];
  const float* tn_b  = (const float*)d_in[18];
  const float* t_wq  = (const float*)d_in[19];
  const float* t_bq  = (const float*)d_in[20];
  const float* t_wk  = (const float*)d_in[21];
  const float* t_bk  = (const float*)d_in[22];
  const float* t_wv  = (const float*)d_in[23];
  const float* t_bv  = (const float*)d_in[24];
  const float* t_wo  = (const float*)d_in[25];
  const float* t_bo  = (const float*)d_in[26];
  const float* mn_g  = (const float*)d_in[27];
  const float* mn_b  = (const float*)d_in[28];
  const float* mw1   = (const float*)d_in[29];
  const float* mb1   = (const float*)d_in[30];
  const float* mw2   = (const float*)d_in[31];
  const float* mb2   = (const float*)d_in[32];
  const float* fn_g  = (const float*)d_in[33];
  const float* fn_b  = (const float*)d_in[34];

  const size_t NX = 4456448;               // B*T1*HW*D
  bf16* Xb  = (bf16*)d_ws;                 // residual stream, bf16
  bf16* XNb = Xb  + NX;
  bf16* Qb  = XNb + NX;
  bf16* Kb  = Qb  + NX;
  bf16* Vb  = Kb  + NX;
  bf16* Wt  = Vb  + NX;                    // 6 layers x 3,145,728 bf16
  bf16* HIDb= Qb;                          // [8704][1024] bf16, aliases Qb+Kb

  float* out0 = (float*)d_out;
  float* out1 = out0 + NX;
  float* out2 = out1 + 1183744;
  float* out3 = out2 + 25165824;

  const int RS = B__*T_*HWL;           // 8192
  const int RT = B__*T1_*HWL;          // 8704
  dim3 gQs(12, 64);
  dim3 gQt(12, 68);
  dim3 g64s(8, 128);                   // N=512, M=8192 (64^2)
  dim3 g64t(8, 136);                   // N=512, M=8704 (64^2)
  dim3 gM1(8, 68);                     // MLP1: N=1024, 128^2 tiles
  dim3 wcg(32, 32, 60);

  embed_ln_kernel<<<RT/4, 256, 0, stream>>>(codes, emb, cls, hpos, wpos, eng, enb, Xb);
  wconv_kernel<<<wcg,256,0,stream>>>(s_wq, s_wk, s_wv, s_wo, t_wq, t_wk, t_wv, t_wo, mw1, mw2, Wt);

  for(int i=0;i<6;i++){
    bf16* Wl = Wt + (size_t)i*3145728;
    // ---- spatial windowed attention ----
    ln_bf_kernel<<<RS/4,256,0,stream>>>(Xb, XNb, sn_g+i*D_, sn_b+i*D_, T_*HWL, T1_*HWL);
    gemm_qkv<<<gQs,256,0,stream>>>(XNb, Wl, s_bq+i*D_, s_bk+i*D_, s_bv+i*D_, Qb, Kb, Vb);
    spatial_attn_kernel<<<256,256,0,stream>>>(Qb, Kb, Vb, XNb);
    gemm_mfma64<<<g64s,256,0,stream>>>(XNb, Wl+3*262144, s_bo+i*D_, Xb, Xb, 512, 512, T_*HWL, T1_*HWL);
    // ---- temporal RoPE causal attention (fused) ----
    ln_bf_kernel<<<RT/4,256,0,stream>>>(Xb, XNb, tn_g+i*D_, tn_b+i*D_, T1_*HWL, T1_*HWL);
    gemm_qkv<<<gQt,256,0,stream>>>(XNb, Wl+4*262144, t_bq+i*D_, t_bk+i*D_, t_bv+i*D_, Qb, Kb, Vb);
    fused_tattn<<<512,512,0,stream>>>(Qb, Kb, Vb, XNb,
                                      out2+(size_t)i*4194304, out3+(size_t)i*4194304,
                                      out1, (i==5)?1:0);
    gemm_mfma64<<<g64t,256,0,stream>>>(XNb, Wl+7*262144, t_bo+i*D_, Xb, Xb, 512, 512, RT, RT);
    avg_frame0_kernel<<<16,256,0,stream>>>(Xb);
    // ---- MLP ----
    ln_bf_kernel<<<RT/4,256,0,stream>>>(Xb, XNb, mn_g+i*D_, mn_b+i*D_, T1_*HWL, T1_*HWL);
    gemm_mfma<1,false,true ><<<gM1,256,0,stream>>>(XNb, Wl+2097152, mb1+i*1024, HIDb, nullptr, 512, 1024, RT, RT);
    gemm_mfma64<<<g64t,256,0,stream>>>(HIDb, Wl+2621440, mb2+i*D_, Xb, Xb, 1024, 512, RT, RT);
  }
  ln_kernel<<<RT/4,256,0,stream>>>(Xb, out0, fn_g, fn_b, T1_*HWL, T1_*HWL);
}